// Round 8
// baseline (2887.075 us; speedup 1.0000x reference)
//
#include <hip/hip_runtime.h>
#include <cstddef>

#define Bg 128
#define Nn 100
#define Eg 800
#define TNODE 12800
#define TEDGE 102400
#define HD 256
#define NEMB 128
#define REMB 256

typedef short bf8 __attribute__((ext_vector_type(8)));
typedef short bf4 __attribute__((ext_vector_type(4)));
typedef float f4  __attribute__((ext_vector_type(4)));

__device__ __forceinline__ float relu_(float x){ return x > 0.f ? x : 0.f; }
__device__ __forceinline__ float sigm_(float x){ return 1.f/(1.f + __expf(-x)); }
__device__ __forceinline__ float4 ld4(const float* p){ return *(const float4*)p; }
__device__ __forceinline__ void st4(float* p, float4 v){ *(float4*)p = v; }
__device__ __forceinline__ float4 add4(float4 a, float4 b){
    return float4{a.x+b.x, a.y+b.y, a.z+b.z, a.w+b.w};
}
__device__ __forceinline__ float4 relu4(float4 a){
    return float4{relu_(a.x), relu_(a.y), relu_(a.z), relu_(a.w)};
}
__device__ __forceinline__ short f2bf(float f){
    unsigned u = __float_as_uint(f);
    u += 0x7fff + ((u >> 16) & 1);
    return (short)(u >> 16);
}
__device__ __forceinline__ float bf2f(short s){
    return __uint_as_float(((unsigned)(unsigned short)s) << 16);
}
__device__ __forceinline__ void split4(float4 v, bf4& h, bf4& l){
    h.x = f2bf(v.x); l.x = f2bf(v.x - bf2f(h.x));
    h.y = f2bf(v.y); l.y = f2bf(v.y - bf2f(h.y));
    h.z = f2bf(v.z); l.z = f2bf(v.z - bf2f(h.z));
    h.w = f2bf(v.w); l.w = f2bf(v.w - bf2f(h.w));
}
__device__ __forceinline__ f4 mfma_(bf8 a, bf8 b, f4 c){
    return __builtin_amdgcn_mfma_f32_16x16x32_bf16(a, b, c, 0, 0, 0);
}

enum { A_PLAIN=0, A_ADD=1, A_RELUB=2, A_CLAMP=3, A_CAT3=4, A_CAT2R=5 };
enum { E_STORE=0, E_RELU=1, E_BIAS=2, E_BIASRELU=3 };

// ---------- MFMA split-bf16 GEMM: C[M,N] = epi(A[M,K] @ W[N,K]^T), ~f32 accuracy ----------
template<int AM, int EM>
__global__ __launch_bounds__(256, 2)
void mgemm(const float* __restrict__ A0, const float* __restrict__ A1,
           const float* __restrict__ A2, const float* __restrict__ W,
           const float* __restrict__ bias, float* __restrict__ C,
           int M, int N, int K, int lda, int wld)
{
    __shared__ short Ah[128][40], Al[128][40], Bh[128][40], Bl[128][40];
    const int t  = threadIdx.x;
    const int kc = t & 7, lr = t >> 3;
    const int lane = t & 63, wv = t >> 6;
    const int wm = wv >> 1, wn = wv & 1;
    const int frow = lane & 15, fk = (lane >> 4) * 8;
    const int row0 = blockIdx.y * 128, col0 = blockIdx.x * 128;

    f4 acc[4][4] = {};

    for (int k0 = 0; k0 < K; k0 += 32) {
        const int gk = k0 + kc * 4;
        const int kk = kc * 4;
        #pragma unroll
        for (int ri = 0; ri < 4; ri++) {
            int row = lr + 32 * ri;
            int grow = row0 + row;
            float4 v;
            if (AM == A_PLAIN) {
                v = ld4(A0 + (size_t)grow * lda + gk);
            } else if (AM == A_ADD) {
                v = add4(ld4(A0 + (size_t)grow * lda + gk),
                         ld4(A1 + (size_t)grow * lda + gk));
            } else if (AM == A_RELUB) {
                v = relu4(add4(ld4(A0 + (size_t)grow * lda + gk), ld4(A1 + gk)));
            } else if (AM == A_CLAMP) {
                int cr = grow < M ? grow : M - 1;
                v = ld4(A0 + (size_t)cr * lda + gk);
            } else if (AM == A_CAT3) {
                if (gk < HD)        v = ld4(A0 + (size_t)grow * HD + gk);
                else if (gk < 2*HD) v = ld4(A1 + (size_t)grow * HD + gk - HD);
                else                v = ld4(A2 + (size_t)grow * HD + gk - 2*HD);
            } else { // A_CAT2R
                v = (gk < HD) ? relu4(ld4(A0 + (size_t)grow * HD + gk))
                              : relu4(ld4(A1 + (size_t)grow * HD + gk - HD));
            }
            bf4 h, l; split4(v, h, l);
            *(bf4*)&Ah[row][kk] = h;
            *(bf4*)&Al[row][kk] = l;
        }
        #pragma unroll
        for (int ri = 0; ri < 4; ri++) {
            int wr = lr + 32 * ri;
            float4 v = ld4(W + (size_t)(col0 + wr) * wld + gk);
            bf4 h, l; split4(v, h, l);
            *(bf4*)&Bh[wr][kk] = h;
            *(bf4*)&Bl[wr][kk] = l;
        }
        __syncthreads();
        bf8 ah[4], al[4], bh[4], bl[4];
        #pragma unroll
        for (int mi = 0; mi < 4; mi++) {
            ah[mi] = *(const bf8*)&Ah[wm*64 + mi*16 + frow][fk];
            al[mi] = *(const bf8*)&Al[wm*64 + mi*16 + frow][fk];
        }
        #pragma unroll
        for (int ni = 0; ni < 4; ni++) {
            bh[ni] = *(const bf8*)&Bh[wn*64 + ni*16 + frow][fk];
            bl[ni] = *(const bf8*)&Bl[wn*64 + ni*16 + frow][fk];
        }
        #pragma unroll
        for (int mi = 0; mi < 4; mi++)
            #pragma unroll
            for (int ni = 0; ni < 4; ni++) {
                acc[mi][ni] = mfma_(ah[mi], bh[ni], acc[mi][ni]);
                acc[mi][ni] = mfma_(ah[mi], bl[ni], acc[mi][ni]);
                acc[mi][ni] = mfma_(al[mi], bh[ni], acc[mi][ni]);
            }
        __syncthreads();
    }
    #pragma unroll
    for (int mi = 0; mi < 4; mi++) {
        #pragma unroll
        for (int ni = 0; ni < 4; ni++) {
            int ccol = col0 + wn*64 + ni*16 + frow;
            int rbase = row0 + wm*64 + mi*16 + (lane >> 4) * 4;
            #pragma unroll
            for (int reg = 0; reg < 4; reg++) {
                float v = acc[mi][ni][reg];
                if (EM == E_BIAS || EM == E_BIASRELU) v += bias[ccol];
                if (EM == E_RELU || EM == E_BIASRELU) v = relu_(v);
                C[(size_t)(rbase + reg) * N + ccol] = v;
            }
        }
    }
}

// ---------- MFMA attention over reconstructed edge features ----------
template<int MODE>
__global__ __launch_bounds__(256, 2)
void mattn(const float* __restrict__ S, const float* __restrict__ Rt,
           const float* __restrict__ D, const float* __restrict__ T0,
           const int* __restrict__ esrc, const int* __restrict__ erel,
           const int* __restrict__ edst,
           const float* __restrict__ W1, const float* __restrict__ W2,
           const float* __restrict__ term, float* __restrict__ sbuf)
{
    __shared__ short Ah[64][40], Al[64][40], Bh[256][40], Bl[256][40];
    __shared__ float partl[4][64];
    __shared__ int isrc[64], irel[64], idst[64];
    const int t = threadIdx.x;
    const int kc = t & 7, lr = t >> 3;
    const int lane = t & 63, wv = t >> 6;
    const int frow = lane & 15, fk = (lane >> 4) * 8;
    const int r0 = blockIdx.x * 64;

    if (t < 64) {
        int e = r0 + t;
        isrc[t] = esrc[e]; irel[t] = erel[e]; idst[t] = edst[e];
    }
    __syncthreads();

    f4 acc[4][4] = {};

    for (int k0 = 0; k0 < HD; k0 += 32) {
        const int gk = k0 + kc * 4;
        const int kk = kc * 4;
        #pragma unroll
        for (int ri = 0; ri < 2; ri++) {
            int row = lr + 32 * ri;
            int s = isrc[row], rl = irel[row], dd = idst[row];
            float4 v = relu4(add4(add4(ld4(S + (size_t)s * HD + gk),
                                       ld4(Rt + (size_t)rl * HD + gk)),
                                  ld4(D + (size_t)dd * HD + gk)));
            if (MODE) v = relu4(add4(v, ld4(T0 + (size_t)s * HD + gk)));
            bf4 h, l; split4(v, h, l);
            *(bf4*)&Ah[row][kk] = h;
            *(bf4*)&Al[row][kk] = l;
        }
        #pragma unroll
        for (int ri = 0; ri < 8; ri++) {
            int wr = lr + 32 * ri;
            float4 v = ld4(W1 + (size_t)wr * 512 + gk);   // left half of [256,512]
            bf4 h, l; split4(v, h, l);
            *(bf4*)&Bh[wr][kk] = h;
            *(bf4*)&Bl[wr][kk] = l;
        }
        __syncthreads();
        bf8 ah[4], al[4], bh[4], bl[4];
        #pragma unroll
        for (int mi = 0; mi < 4; mi++) {
            ah[mi] = *(const bf8*)&Ah[mi*16 + frow][fk];
            al[mi] = *(const bf8*)&Al[mi*16 + frow][fk];
        }
        #pragma unroll
        for (int ni = 0; ni < 4; ni++) {
            bh[ni] = *(const bf8*)&Bh[wv*64 + ni*16 + frow][fk];
            bl[ni] = *(const bf8*)&Bl[wv*64 + ni*16 + frow][fk];
        }
        #pragma unroll
        for (int mi = 0; mi < 4; mi++)
            #pragma unroll
            for (int ni = 0; ni < 4; ni++) {
                acc[mi][ni] = mfma_(ah[mi], bh[ni], acc[mi][ni]);
                acc[mi][ni] = mfma_(ah[mi], bl[ni], acc[mi][ni]);
                acc[mi][ni] = mfma_(al[mi], bh[ni], acc[mi][ni]);
            }
        __syncthreads();
    }
    #pragma unroll
    for (int mi = 0; mi < 4; mi++) {
        #pragma unroll
        for (int reg = 0; reg < 4; reg++) {
            int rl = mi*16 + (lane >> 4) * 4 + reg;
            int g = (r0 + rl) / Eg;
            float p = 0.f;
            #pragma unroll
            for (int ni = 0; ni < 4; ni++) {
                int n = wv*64 + ni*16 + frow;
                p += tanhf(acc[mi][ni][reg] + term[g*HD + n]) * W2[n];
            }
            p += __shfl_xor(p, 1); p += __shfl_xor(p, 2);
            p += __shfl_xor(p, 4); p += __shfl_xor(p, 8);
            if (frow == 0) partl[wv][rl] = p;
        }
    }
    __syncthreads();
    if (t < 64) {
        float p = partl[0][t] + partl[1][t] + partl[2][t] + partl[3][t];
        sbuf[r0 + t] = sigm_(p);
    }
}

// ------- CSR-gather aggregation: agg[n] = sum_{e: dst[e]==n} me(e) * s[e] -------
template<int MODE>
__global__ __launch_bounds__(256)
void agg_gather(const float* __restrict__ S, const float* __restrict__ Rt,
                const float* __restrict__ D, const float* __restrict__ T0,
                const int* __restrict__ esrc, const int* __restrict__ erel,
                const int* __restrict__ rowptr, const int* __restrict__ eidx,
                const float* __restrict__ s, float* __restrict__ agg)
{
    int node = blockIdx.x * 4 + (threadIdx.x >> 6);
    int c = (threadIdx.x & 63) * 4;
    float4 dn = ld4(D + (size_t)node * HD + c);   // dst row constant per node
    float4 acc{0.f, 0.f, 0.f, 0.f};
    int beg = rowptr[node], end = rowptr[node + 1];
    for (int i = beg; i < end; i++) {
        int e = eidx[i];
        int sr = esrc[e], rl = erel[e];
        float4 v = relu4(add4(add4(ld4(S + (size_t)sr * HD + c),
                                   ld4(Rt + (size_t)rl * HD + c)), dn));
        if (MODE) v = relu4(add4(v, ld4(T0 + (size_t)sr * HD + c)));
        float sc = s[e];
        acc.x += v.x * sc; acc.y += v.y * sc;
        acc.z += v.z * sc; acc.w += v.w * sc;
    }
    st4(agg + (size_t)node * HD + c, acc);
}

// ------------- CSR build -------------
__global__ void zeroi_kernel(int* __restrict__ p)
{
    p[blockIdx.x * 256 + threadIdx.x] = 0;
}
__global__ void csr_count(const int* __restrict__ dst, int* __restrict__ cnt)
{
    int e = blockIdx.x * 256 + threadIdx.x;
    atomicAdd(&cnt[dst[e]], 1);
}
__global__ void csr_scan(const int* __restrict__ cnt, int* __restrict__ rowptr)
{
    __shared__ int ws[4];
    __shared__ int carry;
    int tid = threadIdx.x;
    if (tid == 0) carry = 0;
    __syncthreads();
    for (int i = 0; i < TNODE; i += 256) {
        int v = cnt[i + tid];
        int x = v;
        #pragma unroll
        for (int off = 1; off < 64; off <<= 1) {
            int y = __shfl_up(x, off);
            if ((tid & 63) >= off) x += y;
        }
        if ((tid & 63) == 63) ws[tid >> 6] = x;
        __syncthreads();
        int add = carry;
        int w = tid >> 6;
        for (int j = 0; j < w; j++) add += ws[j];
        rowptr[i + tid] = add + x - v;      // exclusive
        __syncthreads();
        if (tid == 255) carry = add + x;
        __syncthreads();
    }
    if (tid == 0) rowptr[TNODE] = carry;
}
__global__ void csr_fill(const int* __restrict__ dst, const int* __restrict__ rowptr,
                         int* __restrict__ fillc, int* __restrict__ eidx)
{
    int e = blockIdx.x * 256 + threadIdx.x;
    int d = dst[e];
    int slot = rowptr[d] + atomicAdd(&fillc[d], 1);
    eidx[slot] = e;
}

// ------------- per-graph attention bias terms -------------
__global__ __launch_bounds__(256)
void term_kernel(const float* __restrict__ mn, const float* __restrict__ tgt_rel,
                 const float* __restrict__ Wa1, const float* __restrict__ Wd1,
                 const int* __restrict__ srcn, const int* __restrict__ tgtn,
                 float* __restrict__ term)
{
    __shared__ float Gs[HD];
    int b = blockIdx.x % Bg;
    int which = blockIdx.x / Bg;
    int c = threadIdx.x;
    float g;
    if (which == 0)
        g = mn[(size_t)srcn[b]*HD + c] + tgt_rel[b*HD + c] - mn[(size_t)tgtn[b]*HD + c];
    else
        g = tgt_rel[b*HD + c];
    Gs[c] = g;
    __syncthreads();
    const float* W = (which == 0) ? Wa1 : (Wd1 + (size_t)(which-1)*HD*512);
    float p = 0.f;
    for (int k = 0; k < HD; k += 4) {
        float4 w = ld4(W + (size_t)c*512 + 256 + k);
        p = fmaf(Gs[k], w.x, p); p = fmaf(Gs[k+1], w.y, p);
        p = fmaf(Gs[k+2], w.z, p); p = fmaf(Gs[k+3], w.w, p);
    }
    term[(size_t)which*Bg*HD + b*HD + c] = p;
}

__global__ void tgtrel_kernel(const float* __restrict__ rel_emb, const int* __restrict__ batch_rel,
                              float* __restrict__ tgt_rel)
{
    int b = blockIdx.x, c = threadIdx.x;
    tgt_rel[b*HD + c] = rel_emb[(size_t)batch_rel[b]*REMB + c];
}

__global__ void h0_kernel(const float* __restrict__ agg2, float* __restrict__ h0)
{
    int b = blockIdx.x, c = threadIdx.x;
    float m = -1e30f;
    for (int n = 0; n < Nn; n++)
        m = fmaxf(m, agg2[((size_t)b*Nn + n)*HD + c]);
    h0[b*HD + c] = m;
}

// ------------- persistent GRU: 256 blocks = (dir, h-slice of 16, seq-group of 16) -------------
// Weights for this block's 48 rows live in LDS (split-bf16). Per step: MFMA recurrent dot,
// gate epilogue, double-buffered global h exchange, 16-block group barrier.
__global__ __launch_bounds__(256)
void gru_persist(const float* __restrict__ gi_f, const float* __restrict__ gi_b,
                 const float* __restrict__ whh_f, const float* __restrict__ whh_b,
                 const float* __restrict__ bhf, const float* __restrict__ bhb,
                 const float* __restrict__ h0,
                 float* __restrict__ hbuf, unsigned* __restrict__ bar,
                 float* __restrict__ outf, float* __restrict__ outb)
{
    __shared__ short whi[48][264], wlo[48][264];   // 50.7 KB
    __shared__ float gates[3][16][16];
    const int blk = blockIdx.x;            // dir*128 + hsl*8 + grp
    const int d   = blk >> 7;
    const int hsl = (blk >> 3) & 15;
    const int grp = blk & 7;
    const int t0  = threadIdx.x;
    const int lane = t0 & 63, wvv = t0 >> 6;
    const int j16 = lane & 15, koff = (lane >> 4) * 8;

    const float* whh = d ? whh_b : whh_f;
    const float* gi  = d ? gi_b : gi_f;
    const float* bh  = d ? bhb : bhf;
    float* outp      = d ? outb : outf;

    // preload weights: LDS row ro = g*16+j  <-  global row g*256 + hsl*16 + j
    for (int i = t0; i < 48 * 256; i += 256) {
        int ro = i >> 8, k = i & 255;
        int grow = (ro >> 4) * 256 + hsl * 16 + (ro & 15);
        float v = whh[(size_t)grow * 256 + k];
        short hh = f2bf(v);
        whi[ro][k] = hh;
        wlo[ro][k] = f2bf(v - bf2f(hh));
    }
    __syncthreads();

    const int nrow = d * 128 + grp * 16;     // row base in hbuf
    unsigned* barp = bar + (unsigned)(d * 8 + grp) * 16;

    for (int t = 0; t < Nn; t++) {
        const float* hsrc = (t == 0) ? (h0 + (size_t)(grp*16) * HD)
                                     : (hbuf + (size_t)(t & 1) * 65536 + (size_t)nrow * HD);
        if (wvv < 3) {
            f4 acc = {};
            bf8 ahi[8], alo[8];
            const float* hrow = hsrc + (size_t)j16 * HD + koff;
            #pragma unroll
            for (int ks = 0; ks < 8; ks++) {
                float4 v0 = ld4(hrow + ks*32);
                float4 v1 = ld4(hrow + ks*32 + 4);
                bf4 h0_, l0_, h1_, l1_;
                split4(v0, h0_, l0_); split4(v1, h1_, l1_);
                ahi[ks] = bf8{h0_.x,h0_.y,h0_.z,h0_.w, h1_.x,h1_.y,h1_.z,h1_.w};
                alo[ks] = bf8{l0_.x,l0_.y,l0_.z,l0_.w, l1_.x,l1_.y,l1_.z,l1_.w};
            }
            const int bro = wvv * 16 + j16;
            #pragma unroll
            for (int ks = 0; ks < 8; ks++) {
                bf8 bhi = *(const bf8*)&whi[bro][ks*32 + koff];
                bf8 blo = *(const bf8*)&wlo[bro][ks*32 + koff];
                acc = mfma_(ahi[ks], bhi, acc);
                acc = mfma_(ahi[ks], blo, acc);
                acc = mfma_(alo[ks], bhi, acc);
            }
            #pragma unroll
            for (int reg = 0; reg < 4; reg++)
                gates[wvv][(lane >> 4)*4 + reg][j16] = acc[reg];
        }
        __syncthreads();
        {   // epilogue: one (seq, j) per thread
            int s = t0 >> 4, j = t0 & 15;
            int hidx = hsl * 16 + j;
            int trow = d ? (Nn - 1 - t) : t;
            size_t girow = ((size_t)(grp*16 + s) * Nn + trow) * 768;
            float hprev = hsrc[(size_t)s * HD + hidx];
            float r = sigm_(gi[girow + hidx]       + gates[0][s][j] + bh[hidx]);
            float z = sigm_(gi[girow + 256 + hidx] + gates[1][s][j] + bh[256 + hidx]);
            float n = tanhf(gi[girow + 512 + hidx] + r * (gates[2][s][j] + bh[512 + hidx]));
            float nh = (1.f - z) * n + z * hprev;
            outp[((size_t)(grp*16 + s) * Nn + trow) * HD + hidx] = nh;
            hbuf[(size_t)((t + 1) & 1) * 65536 + (size_t)(nrow + s) * HD + hidx] = nh;
        }
        __syncthreads();
        if (t0 == 0) {
            __threadfence();
            __hip_atomic_fetch_add(barp, 1u, __ATOMIC_RELEASE, __HIP_MEMORY_SCOPE_AGENT);
            unsigned tgt = 16u * (unsigned)(t + 1);
            while (__hip_atomic_load(barp, __ATOMIC_ACQUIRE, __HIP_MEMORY_SCOPE_AGENT) < tgt) {}
            __threadfence();
        }
        __syncthreads();
    }
}

__global__ __launch_bounds__(256)
void final_kernel(const float* __restrict__ atom_h, const float* __restrict__ tgt_rel,
                  const int* __restrict__ srcn, const int* __restrict__ tgtn,
                  const float* __restrict__ Wl, const float* __restrict__ bl,
                  float* __restrict__ out)
{
    __shared__ float red[4];
    int b = blockIdx.x, c = threadIdx.x;
    float v = tanhf(atom_h[(size_t)srcn[b]*HD + c] + tgt_rel[b*HD + c]
                    - atom_h[(size_t)tgtn[b]*HD + c]);
    float p = v * Wl[c];
    #pragma unroll
    for (int off = 1; off < 64; off <<= 1) p += __shfl_xor(p, off);
    int wv = c >> 6;
    if ((c & 63) == 0) red[wv] = p;
    __syncthreads();
    if (c == 0) out[b] = red[0] + red[1] + red[2] + red[3] + bl[0];
}

extern "C" void kernel_launch(void* const* d_in, const int* in_sizes, int n_in,
                              void* d_out, int out_size, void* d_ws, size_t ws_size,
                              hipStream_t stream)
{
    const float* node_feat = (const float*)d_in[0];
    const float* rel_emb   = (const float*)d_in[1];
    const float* W_i_node  = (const float*)d_in[2];
    const float* W_i_edge  = (const float*)d_in[3];
    const float* Wa1       = (const float*)d_in[4];
    const float* Wa2       = (const float*)d_in[5];
    const float* W_h_atom  = (const float*)d_in[6];
    const float* W_h_bond  = (const float*)d_in[7];
    const float* Wd1       = (const float*)d_in[8];
    const float* Wd2       = (const float*)d_in[9];
    const float* W_comm    = (const float*)d_in[10];
    const float* gru_bias  = (const float*)d_in[11];
    const float* w_ih_f    = (const float*)d_in[12];
    const float* w_hh_f    = (const float*)d_in[13];
    const float* b_ih_f    = (const float*)d_in[14];
    const float* b_hh_f    = (const float*)d_in[15];
    const float* w_ih_b    = (const float*)d_in[16];
    const float* w_hh_b    = (const float*)d_in[17];
    const float* b_ih_b    = (const float*)d_in[18];
    const float* b_hh_b    = (const float*)d_in[19];
    const float* W_o       = (const float*)d_in[20];
    const float* b_o       = (const float*)d_in[21];
    const float* W_lin1    = (const float*)d_in[22];
    const float* b_lin1    = (const float*)d_in[23];
    const int* edge_src  = (const int*)d_in[24];
    const int* edge_dst  = (const int*)d_in[25];
    const int* edge_rel  = (const int*)d_in[26];
    const int* batch_rel = (const int*)d_in[27];
    const int* src_node  = (const int*)d_in[28];
    const int* tgt_node  = (const int*)d_in[29];
    float* out = (float*)d_out;

    float* ws = (float*)d_ws;
    size_t off = 0;
    auto alloc = [&](size_t n){ float* p = ws + off; off += n; return p; };
    float* tgt_rel    = alloc((size_t)Bg*HD);
    float* term       = alloc((size_t)3*Bg*HD);
    float* input_node = alloc((size_t)TNODE*HD);
    float* mn_a       = alloc((size_t)TNODE*HD);
    float* mn_b       = alloc((size_t)TNODE*HD);
    float* agg        = alloc((size_t)TNODE*HD);
    float* h0v        = alloc((size_t)Bg*HD);
    float* hbuf       = alloc((size_t)2*256*HD);
    unsigned* bar     = (unsigned*)alloc((size_t)256);
    float* sbuf       = alloc((size_t)TEDGE);
    int*   cnt        = (int*)alloc((size_t)TNODE);
    int*   fillc      = (int*)alloc((size_t)TNODE);
    int*   rowptr     = (int*)alloc((size_t)TNODE + 256);
    int*   eidx       = (int*)alloc((size_t)TEDGE);
    float* Sbuf       = alloc((size_t)TNODE*HD);
    float* Dbuf       = alloc((size_t)TNODE*HD);
    float* Rbuf       = alloc((size_t)256*HD);
    float* gi_f       = alloc((size_t)TNODE*768);
    float* gi_b       = alloc((size_t)TNODE*768);
    float* out_f      = alloc((size_t)TNODE*HD);
    float* out_b      = alloc((size_t)TNODE*HD);
    // aliases (lifetimes disjoint):
    float* agg2   = mn_a;        // after last attn/gather
    float* atom_h = input_node;  // after W_comm GEMM

    tgtrel_kernel<<<Bg, 256, 0, stream>>>(rel_emb, batch_rel, tgt_rel);

    // ---- CSR build (dst-sorted incidence) + barrier zero ----
    zeroi_kernel<<<2*TNODE/256, 256, 0, stream>>>(cnt);     // zeros cnt AND fillc (adjacent)
    zeroi_kernel<<<1, 256, 0, stream>>>((int*)bar);
    csr_count<<<TEDGE/256, 256, 0, stream>>>(edge_dst, cnt);
    csr_scan<<<1, 256, 0, stream>>>(cnt, rowptr);
    csr_fill<<<TEDGE/256, 256, 0, stream>>>(edge_dst, rowptr, fillc, eidx);

    // input_node = relu(node_feat @ W_i_node^T)
    mgemm<A_PLAIN, E_RELU><<<dim3(HD/128, TNODE/128), 256, 0, stream>>>(
        node_feat, nullptr, nullptr, W_i_node, nullptr, input_node,
        TNODE, HD, NEMB, NEMB, NEMB);

    // edge-feature factor tables: ie[e] = relu(S[src] + R[rel] + D[dst])
    mgemm<A_PLAIN, E_STORE><<<dim3(HD/128, TNODE/128), 256, 0, stream>>>(
        node_feat, nullptr, nullptr, W_i_edge + 0, nullptr, Sbuf,
        TNODE, HD, NEMB, NEMB, 512);
    mgemm<A_PLAIN, E_STORE><<<dim3(HD/128, TNODE/128), 256, 0, stream>>>(
        node_feat, nullptr, nullptr, W_i_edge + 384, nullptr, Dbuf,
        TNODE, HD, NEMB, NEMB, 512);
    mgemm<A_CLAMP, E_STORE><<<dim3(HD/128, 2), 256, 0, stream>>>(
        rel_emb, nullptr, nullptr, W_i_edge + 128, nullptr, Rbuf,
        200, HD, REMB, REMB, 512);

    term_kernel<<<3*Bg, 256, 0, stream>>>(input_node, tgt_rel, Wa1, Wd1,
                                          src_node, tgt_node, term);

    // ---- input attention scale + gather-aggregate ----
    mattn<0><<<TEDGE/64, 256, 0, stream>>>(Sbuf, Rbuf, Dbuf, Sbuf,
        edge_src, edge_rel, edge_dst, Wa1, Wa2, term, sbuf);
    agg_gather<0><<<TNODE/4, 256, 0, stream>>>(Sbuf, Rbuf, Dbuf, Sbuf,
        edge_src, edge_rel, rowptr, eidx, sbuf, agg);

    const float* mn_cur = input_node;
    float* bufs[2] = {mn_a, mn_b};
    for (int d = 0; d < 2; d++) {
        float* mn_next = bufs[d];
        float* tmp     = bufs[1-d];
        mgemm<A_ADD, E_RELU><<<dim3(2, TNODE/128), 256, 0, stream>>>(
            mn_cur, agg, nullptr, W_h_atom + (size_t)d*HD*HD, nullptr, mn_next,
            TNODE, HD, HD, HD, HD);
        mgemm<A_PLAIN, E_STORE><<<dim3(2, TNODE/128), 256, 0, stream>>>(
            mn_next, nullptr, nullptr, W_h_bond + (size_t)d*HD*HD, nullptr, tmp,
            TNODE, HD, HD, HD, HD);
        mattn<1><<<TEDGE/64, 256, 0, stream>>>(Sbuf, Rbuf, Dbuf, tmp,
            edge_src, edge_rel, edge_dst, Wd1 + (size_t)d*HD*512,
            Wd2 + (size_t)d*HD, term + (size_t)(1+d)*Bg*HD, sbuf);
        agg_gather<1><<<TNODE/4, 256, 0, stream>>>(Sbuf, Rbuf, Dbuf, tmp,
            edge_src, edge_rel, rowptr, eidx, sbuf, agg);
        mn_cur = mn_next;
    }

    // agg2 = concat([agg, mn, input_node]) @ W_comm^T   (agg2 aliases mn_a)
    mgemm<A_CAT3, E_STORE><<<dim3(2, TNODE/128), 256, 0, stream>>>(
        agg, (const float*)mn_cur, input_node, W_comm, nullptr, agg2,
        TNODE, HD, 3*HD, 0, 3*HD);

    h0_kernel<<<Bg, 256, 0, stream>>>(agg2, h0v);

    // gi = relu(agg2 + gru_bias) @ w_ih^T + b_ih   (both directions)
    mgemm<A_RELUB, E_BIAS><<<dim3(768/128, TNODE/128), 256, 0, stream>>>(
        agg2, gru_bias, nullptr, w_ih_f, b_ih_f, gi_f,
        TNODE, 768, HD, HD, HD);
    mgemm<A_RELUB, E_BIAS><<<dim3(768/128, TNODE/128), 256, 0, stream>>>(
        agg2, gru_bias, nullptr, w_ih_b, b_ih_b, gi_b,
        TNODE, 768, HD, HD, HD);

    gru_persist<<<256, 256, 0, stream>>>(gi_f, gi_b, w_hh_f, w_hh_b,
                                         b_hh_f, b_hh_b, h0v, hbuf, bar,
                                         out_f, out_b);

    // atom_h = relu(relu(concat(out_f,out_b)) @ W_o^T + b_o)
    mgemm<A_CAT2R, E_BIASRELU><<<dim3(2, TNODE/128), 256, 0, stream>>>(
        out_f, out_b, nullptr, W_o, b_o, atom_h,
        TNODE, HD, 2*HD, 0, 2*HD);

    final_kernel<<<Bg, 256, 0, stream>>>(atom_h, tgt_rel, src_node, tgt_node,
                                         W_lin1, b_lin1, out);
}

// Round 9
// 1952.287 us; speedup vs baseline: 1.4788x; 1.4788x over previous
//
#include <hip/hip_runtime.h>
#include <cstddef>

#define Bg 128
#define Nn 100
#define Eg 800
#define TNODE 12800
#define TEDGE 102400
#define HD 256
#define NEMB 128
#define REMB 256

typedef short bf8 __attribute__((ext_vector_type(8)));
typedef short bf4 __attribute__((ext_vector_type(4)));
typedef float f4  __attribute__((ext_vector_type(4)));

__device__ __forceinline__ float relu_(float x){ return x > 0.f ? x : 0.f; }
__device__ __forceinline__ float sigm_(float x){ return 1.f/(1.f + __expf(-x)); }
__device__ __forceinline__ float4 ld4(const float* p){ return *(const float4*)p; }
__device__ __forceinline__ void st4(float* p, float4 v){ *(float4*)p = v; }
__device__ __forceinline__ float4 add4(float4 a, float4 b){
    return float4{a.x+b.x, a.y+b.y, a.z+b.z, a.w+b.w};
}
__device__ __forceinline__ float4 relu4(float4 a){
    return float4{relu_(a.x), relu_(a.y), relu_(a.z), relu_(a.w)};
}
__device__ __forceinline__ short f2bf(float f){
    unsigned u = __float_as_uint(f);
    u += 0x7fff + ((u >> 16) & 1);
    return (short)(u >> 16);
}
__device__ __forceinline__ float bf2f(short s){
    return __uint_as_float(((unsigned)(unsigned short)s) << 16);
}
__device__ __forceinline__ void split4(float4 v, bf4& h, bf4& l){
    h.x = f2bf(v.x); l.x = f2bf(v.x - bf2f(h.x));
    h.y = f2bf(v.y); l.y = f2bf(v.y - bf2f(h.y));
    h.z = f2bf(v.z); l.z = f2bf(v.z - bf2f(h.z));
    h.w = f2bf(v.w); l.w = f2bf(v.w - bf2f(h.w));
}
__device__ __forceinline__ f4 mfma_(bf8 a, bf8 b, f4 c){
    return __builtin_amdgcn_mfma_f32_16x16x32_bf16(a, b, c, 0, 0, 0);
}

enum { A_PLAIN=0, A_ADD=1, A_RELUB=2, A_CLAMP=3, A_CAT3=4, A_CAT2R=5 };
enum { E_STORE=0, E_RELU=1, E_BIAS=2, E_BIASRELU=3 };

// ---------- MFMA split-bf16 GEMM: C[M,N] = epi(A[M,K] @ W[N,K]^T), ~f32 accuracy ----------
template<int AM, int EM>
__global__ __launch_bounds__(256, 2)
void mgemm(const float* __restrict__ A0, const float* __restrict__ A1,
           const float* __restrict__ A2, const float* __restrict__ W,
           const float* __restrict__ bias, float* __restrict__ C,
           int M, int N, int K, int lda, int wld)
{
    __shared__ short Ah[128][40], Al[128][40], Bh[128][40], Bl[128][40];
    const int t  = threadIdx.x;
    const int kc = t & 7, lr = t >> 3;
    const int lane = t & 63, wv = t >> 6;
    const int wm = wv >> 1, wn = wv & 1;
    const int frow = lane & 15, fk = (lane >> 4) * 8;
    const int row0 = blockIdx.y * 128, col0 = blockIdx.x * 128;

    f4 acc[4][4] = {};

    for (int k0 = 0; k0 < K; k0 += 32) {
        const int gk = k0 + kc * 4;
        const int kk = kc * 4;
        #pragma unroll
        for (int ri = 0; ri < 4; ri++) {
            int row = lr + 32 * ri;
            int grow = row0 + row;
            float4 v;
            if (AM == A_PLAIN) {
                v = ld4(A0 + (size_t)grow * lda + gk);
            } else if (AM == A_ADD) {
                v = add4(ld4(A0 + (size_t)grow * lda + gk),
                         ld4(A1 + (size_t)grow * lda + gk));
            } else if (AM == A_RELUB) {
                v = relu4(add4(ld4(A0 + (size_t)grow * lda + gk), ld4(A1 + gk)));
            } else if (AM == A_CLAMP) {
                int cr = grow < M ? grow : M - 1;
                v = ld4(A0 + (size_t)cr * lda + gk);
            } else if (AM == A_CAT3) {
                if (gk < HD)        v = ld4(A0 + (size_t)grow * HD + gk);
                else if (gk < 2*HD) v = ld4(A1 + (size_t)grow * HD + gk - HD);
                else                v = ld4(A2 + (size_t)grow * HD + gk - 2*HD);
            } else { // A_CAT2R
                v = (gk < HD) ? relu4(ld4(A0 + (size_t)grow * HD + gk))
                              : relu4(ld4(A1 + (size_t)grow * HD + gk - HD));
            }
            bf4 h, l; split4(v, h, l);
            *(bf4*)&Ah[row][kk] = h;
            *(bf4*)&Al[row][kk] = l;
        }
        #pragma unroll
        for (int ri = 0; ri < 4; ri++) {
            int wr = lr + 32 * ri;
            float4 v = ld4(W + (size_t)(col0 + wr) * wld + gk);
            bf4 h, l; split4(v, h, l);
            *(bf4*)&Bh[wr][kk] = h;
            *(bf4*)&Bl[wr][kk] = l;
        }
        __syncthreads();
        bf8 ah[4], al[4], bh[4], bl[4];
        #pragma unroll
        for (int mi = 0; mi < 4; mi++) {
            ah[mi] = *(const bf8*)&Ah[wm*64 + mi*16 + frow][fk];
            al[mi] = *(const bf8*)&Al[wm*64 + mi*16 + frow][fk];
        }
        #pragma unroll
        for (int ni = 0; ni < 4; ni++) {
            bh[ni] = *(const bf8*)&Bh[wn*64 + ni*16 + frow][fk];
            bl[ni] = *(const bf8*)&Bl[wn*64 + ni*16 + frow][fk];
        }
        #pragma unroll
        for (int mi = 0; mi < 4; mi++)
            #pragma unroll
            for (int ni = 0; ni < 4; ni++) {
                acc[mi][ni] = mfma_(ah[mi], bh[ni], acc[mi][ni]);
                acc[mi][ni] = mfma_(ah[mi], bl[ni], acc[mi][ni]);
                acc[mi][ni] = mfma_(al[mi], bh[ni], acc[mi][ni]);
            }
        __syncthreads();
    }
    #pragma unroll
    for (int mi = 0; mi < 4; mi++) {
        #pragma unroll
        for (int ni = 0; ni < 4; ni++) {
            int ccol = col0 + wn*64 + ni*16 + frow;
            int rbase = row0 + wm*64 + mi*16 + (lane >> 4) * 4;
            #pragma unroll
            for (int reg = 0; reg < 4; reg++) {
                float v = acc[mi][ni][reg];
                if (EM == E_BIAS || EM == E_BIASRELU) v += bias[ccol];
                if (EM == E_RELU || EM == E_BIASRELU) v = relu_(v);
                C[(size_t)(rbase + reg) * N + ccol] = v;
            }
        }
    }
}

// ---------- MFMA attention over reconstructed edge features ----------
template<int MODE>
__global__ __launch_bounds__(256, 2)
void mattn(const float* __restrict__ S, const float* __restrict__ Rt,
           const float* __restrict__ D, const float* __restrict__ T0,
           const int* __restrict__ esrc, const int* __restrict__ erel,
           const int* __restrict__ edst,
           const float* __restrict__ W1, const float* __restrict__ W2,
           const float* __restrict__ term, float* __restrict__ sbuf)
{
    __shared__ short Ah[64][40], Al[64][40], Bh[256][40], Bl[256][40];
    __shared__ float partl[4][64];
    __shared__ int isrc[64], irel[64], idst[64];
    const int t = threadIdx.x;
    const int kc = t & 7, lr = t >> 3;
    const int lane = t & 63, wv = t >> 6;
    const int frow = lane & 15, fk = (lane >> 4) * 8;
    const int r0 = blockIdx.x * 64;

    if (t < 64) {
        int e = r0 + t;
        isrc[t] = esrc[e]; irel[t] = erel[e]; idst[t] = edst[e];
    }
    __syncthreads();

    f4 acc[4][4] = {};

    for (int k0 = 0; k0 < HD; k0 += 32) {
        const int gk = k0 + kc * 4;
        const int kk = kc * 4;
        #pragma unroll
        for (int ri = 0; ri < 2; ri++) {
            int row = lr + 32 * ri;
            int s = isrc[row], rl = irel[row], dd = idst[row];
            float4 v = relu4(add4(add4(ld4(S + (size_t)s * HD + gk),
                                       ld4(Rt + (size_t)rl * HD + gk)),
                                  ld4(D + (size_t)dd * HD + gk)));
            if (MODE) v = relu4(add4(v, ld4(T0 + (size_t)s * HD + gk)));
            bf4 h, l; split4(v, h, l);
            *(bf4*)&Ah[row][kk] = h;
            *(bf4*)&Al[row][kk] = l;
        }
        #pragma unroll
        for (int ri = 0; ri < 8; ri++) {
            int wr = lr + 32 * ri;
            float4 v = ld4(W1 + (size_t)wr * 512 + gk);   // left half of [256,512]
            bf4 h, l; split4(v, h, l);
            *(bf4*)&Bh[wr][kk] = h;
            *(bf4*)&Bl[wr][kk] = l;
        }
        __syncthreads();
        bf8 ah[4], al[4], bh[4], bl[4];
        #pragma unroll
        for (int mi = 0; mi < 4; mi++) {
            ah[mi] = *(const bf8*)&Ah[mi*16 + frow][fk];
            al[mi] = *(const bf8*)&Al[mi*16 + frow][fk];
        }
        #pragma unroll
        for (int ni = 0; ni < 4; ni++) {
            bh[ni] = *(const bf8*)&Bh[wv*64 + ni*16 + frow][fk];
            bl[ni] = *(const bf8*)&Bl[wv*64 + ni*16 + frow][fk];
        }
        #pragma unroll
        for (int mi = 0; mi < 4; mi++)
            #pragma unroll
            for (int ni = 0; ni < 4; ni++) {
                acc[mi][ni] = mfma_(ah[mi], bh[ni], acc[mi][ni]);
                acc[mi][ni] = mfma_(ah[mi], bl[ni], acc[mi][ni]);
                acc[mi][ni] = mfma_(al[mi], bh[ni], acc[mi][ni]);
            }
        __syncthreads();
    }
    #pragma unroll
    for (int mi = 0; mi < 4; mi++) {
        #pragma unroll
        for (int reg = 0; reg < 4; reg++) {
            int rl = mi*16 + (lane >> 4) * 4 + reg;
            int g = (r0 + rl) / Eg;
            float p = 0.f;
            #pragma unroll
            for (int ni = 0; ni < 4; ni++) {
                int n = wv*64 + ni*16 + frow;
                p += tanhf(acc[mi][ni][reg] + term[g*HD + n]) * W2[n];
            }
            p += __shfl_xor(p, 1); p += __shfl_xor(p, 2);
            p += __shfl_xor(p, 4); p += __shfl_xor(p, 8);
            if (frow == 0) partl[wv][rl] = p;
        }
    }
    __syncthreads();
    if (t < 64) {
        float p = partl[0][t] + partl[1][t] + partl[2][t] + partl[3][t];
        sbuf[r0 + t] = sigm_(p);
    }
}

// ------- CSR-gather aggregation: agg[n] = sum_{e: dst[e]==n} me(e) * s[e] -------
template<int MODE>
__global__ __launch_bounds__(256)
void agg_gather(const float* __restrict__ S, const float* __restrict__ Rt,
                const float* __restrict__ D, const float* __restrict__ T0,
                const int* __restrict__ esrc, const int* __restrict__ erel,
                const int* __restrict__ rowptr, const int* __restrict__ eidx,
                const float* __restrict__ s, float* __restrict__ agg)
{
    int node = blockIdx.x * 4 + (threadIdx.x >> 6);
    int c = (threadIdx.x & 63) * 4;
    float4 dn = ld4(D + (size_t)node * HD + c);   // dst row constant per node
    float4 acc{0.f, 0.f, 0.f, 0.f};
    int beg = rowptr[node], end = rowptr[node + 1];
    for (int i = beg; i < end; i++) {
        int e = eidx[i];
        int sr = esrc[e], rl = erel[e];
        float4 v = relu4(add4(add4(ld4(S + (size_t)sr * HD + c),
                                   ld4(Rt + (size_t)rl * HD + c)), dn));
        if (MODE) v = relu4(add4(v, ld4(T0 + (size_t)sr * HD + c)));
        float sc = s[e];
        acc.x += v.x * sc; acc.y += v.y * sc;
        acc.z += v.z * sc; acc.w += v.w * sc;
    }
    st4(agg + (size_t)node * HD + c, acc);
}

// ------------- CSR build -------------
__global__ void zeroi_kernel(int* __restrict__ p)
{
    p[blockIdx.x * 256 + threadIdx.x] = 0;
}
__global__ void csr_count(const int* __restrict__ dst, int* __restrict__ cnt)
{
    int e = blockIdx.x * 256 + threadIdx.x;
    atomicAdd(&cnt[dst[e]], 1);
}
__global__ void csr_scan(const int* __restrict__ cnt, int* __restrict__ rowptr)
{
    __shared__ int ws[4];
    __shared__ int carry;
    int tid = threadIdx.x;
    if (tid == 0) carry = 0;
    __syncthreads();
    for (int i = 0; i < TNODE; i += 256) {
        int v = cnt[i + tid];
        int x = v;
        #pragma unroll
        for (int off = 1; off < 64; off <<= 1) {
            int y = __shfl_up(x, off);
            if ((tid & 63) >= off) x += y;
        }
        if ((tid & 63) == 63) ws[tid >> 6] = x;
        __syncthreads();
        int add = carry;
        int w = tid >> 6;
        for (int j = 0; j < w; j++) add += ws[j];
        rowptr[i + tid] = add + x - v;      // exclusive
        __syncthreads();
        if (tid == 255) carry = add + x;
        __syncthreads();
    }
    if (tid == 0) rowptr[TNODE] = carry;
}
__global__ void csr_fill(const int* __restrict__ dst, const int* __restrict__ rowptr,
                         int* __restrict__ fillc, int* __restrict__ eidx)
{
    int e = blockIdx.x * 256 + threadIdx.x;
    int d = dst[e];
    int slot = rowptr[d] + atomicAdd(&fillc[d], 1);
    eidx[slot] = e;
}

// ------------- per-graph attention bias terms -------------
__global__ __launch_bounds__(256)
void term_kernel(const float* __restrict__ mn, const float* __restrict__ tgt_rel,
                 const float* __restrict__ Wa1, const float* __restrict__ Wd1,
                 const int* __restrict__ srcn, const int* __restrict__ tgtn,
                 float* __restrict__ term)
{
    __shared__ float Gs[HD];
    int b = blockIdx.x % Bg;
    int which = blockIdx.x / Bg;
    int c = threadIdx.x;
    float g;
    if (which == 0)
        g = mn[(size_t)srcn[b]*HD + c] + tgt_rel[b*HD + c] - mn[(size_t)tgtn[b]*HD + c];
    else
        g = tgt_rel[b*HD + c];
    Gs[c] = g;
    __syncthreads();
    const float* W = (which == 0) ? Wa1 : (Wd1 + (size_t)(which-1)*HD*512);
    float p = 0.f;
    for (int k = 0; k < HD; k += 4) {
        float4 w = ld4(W + (size_t)c*512 + 256 + k);
        p = fmaf(Gs[k], w.x, p); p = fmaf(Gs[k+1], w.y, p);
        p = fmaf(Gs[k+2], w.z, p); p = fmaf(Gs[k+3], w.w, p);
    }
    term[(size_t)which*Bg*HD + b*HD + c] = p;
}

__global__ void tgtrel_kernel(const float* __restrict__ rel_emb, const int* __restrict__ batch_rel,
                              float* __restrict__ tgt_rel)
{
    int b = blockIdx.x, c = threadIdx.x;
    tgt_rel[b*HD + c] = rel_emb[(size_t)batch_rel[b]*REMB + c];
}

__global__ void h0_kernel(const float* __restrict__ agg2, float* __restrict__ h0)
{
    int b = blockIdx.x, c = threadIdx.x;
    float m = -1e30f;
    for (int n = 0; n < Nn; n++)
        m = fmaxf(m, agg2[((size_t)b*Nn + n)*HD + c]);
    h0[b*HD + c] = m;
}

// ------------- convert w_hh to bf16: whbf[d][row][k] -------------
__global__ void whbf_kernel(const float* __restrict__ whf, const float* __restrict__ whb,
                            short* __restrict__ whbf)
{
    int idx = blockIdx.x * 256 + threadIdx.x;   // 2*768*256
    int d = idx / (768*256), rem = idx % (768*256);
    whbf[idx] = f2bf((d ? whb : whf)[rem]);
}

// ------------- GRU: 16 blocks = (dir, grp of 16 seqs); block-local recurrence -------------
// Per step: stream bf16 weight panel (768x256) from L2, MFMA (A = h split hi/lo from LDS,
// shared across waves; B = weight rows), gates via LDS, epilogue. No cross-block sync.
__global__ __launch_bounds__(1024)
void gru_seq(const float* __restrict__ gi_f, const float* __restrict__ gi_b,
             const short* __restrict__ whbf,
             const float* __restrict__ bhf, const float* __restrict__ bhb,
             const float* __restrict__ h0,
             float* __restrict__ outf, float* __restrict__ outb)
{
    __shared__ float hs[16][260];       // h state, f32
    __shared__ float gates[768][17];    // [gate*256+h][seq]
    const int blk = blockIdx.x;         // dir*8 + grp
    const int d = blk >> 3, grp = blk & 7;
    const int tid = threadIdx.x;
    const int lane = tid & 63, wv = tid >> 6;   // 16 waves
    const int f16 = lane & 15;          // A row (seq) / B row (wrow) within tile
    const int kb  = (lane >> 4) * 8;    // k sub-offset

    const short* wp0 = whbf + (size_t)d * 768 * 256;
    const float* gi  = d ? gi_b : gi_f;
    const float* bh  = d ? bhb : bhf;
    float* outp      = d ? outb : outf;

    {   // init h
        int seq = tid >> 6, hb = tid & 63;
        #pragma unroll
        for (int hh = 0; hh < 4; hh++) {
            int h = hb + hh * 64;
            hs[seq][h] = h0[(size_t)(grp*16 + seq) * HD + h];
        }
    }
    __syncthreads();

    for (int t = 0; t < Nn; t++) {
        // --- A fragments: h[seq=f16][k], split hi/lo (shared across all 3 tiles) ---
        bf8 ahi[8], alo[8];
        {
            const float* hrow = &hs[f16][kb];
            #pragma unroll
            for (int ks = 0; ks < 8; ks++) {
                float4 v0 = ld4(hrow + ks*32);
                float4 v1 = ld4(hrow + ks*32 + 4);
                bf4 h0_, l0_, h1_, l1_;
                split4(v0, h0_, l0_); split4(v1, h1_, l1_);
                ahi[ks] = bf8{h0_.x,h0_.y,h0_.z,h0_.w, h1_.x,h1_.y,h1_.z,h1_.w};
                alo[ks] = bf8{l0_.x,l0_.y,l0_.z,l0_.w, l1_.x,l1_.y,l1_.z,l1_.w};
            }
        }
        // --- 3 n-tiles per wave: wrows [ (wv*3+j)*16 , +16 ) ---
        #pragma unroll
        for (int j = 0; j < 3; j++) {
            int wr = (wv*3 + j) * 16 + f16;
            const short* wp = wp0 + (size_t)wr * 256 + kb;
            f4 acc = {};
            #pragma unroll
            for (int ks = 0; ks < 8; ks++) {
                bf8 b = *(const bf8*)(wp + ks*32);
                acc = mfma_(ahi[ks], b, acc);
                acc = mfma_(alo[ks], b, acc);
            }
            #pragma unroll
            for (int reg = 0; reg < 4; reg++)
                gates[(wv*3 + j)*16 + f16][(lane >> 4)*4 + reg] = acc[reg];
        }
        __syncthreads();
        // --- epilogue: thread owns (seq, h) for 4 h values ---
        {
            int seq = tid >> 6, hb = tid & 63;
            int trow = d ? (Nn - 1 - t) : t;
            size_t girow = ((size_t)(grp*16 + seq) * Nn + trow) * 768;
            size_t orow  = ((size_t)(grp*16 + seq) * Nn + trow) * HD;
            #pragma unroll
            for (int hh = 0; hh < 4; hh++) {
                int h = hb + hh * 64;
                float R  = gates[h][seq];
                float Z  = gates[256 + h][seq];
                float NN = gates[512 + h][seq];
                float hprev = hs[seq][h];
                float r = sigm_(gi[girow + h]       + R  + bh[h]);
                float z = sigm_(gi[girow + 256 + h] + Z  + bh[256 + h]);
                float n = tanhf(gi[girow + 512 + h] + r * (NN + bh[512 + h]));
                float nh = (1.f - z) * n + z * hprev;
                hs[seq][h] = nh;
                outp[orow + h] = nh;
            }
        }
        __syncthreads();
    }
}

__global__ __launch_bounds__(256)
void final_kernel(const float* __restrict__ atom_h, const float* __restrict__ tgt_rel,
                  const int* __restrict__ srcn, const int* __restrict__ tgtn,
                  const float* __restrict__ Wl, const float* __restrict__ bl,
                  float* __restrict__ out)
{
    __shared__ float red[4];
    int b = blockIdx.x, c = threadIdx.x;
    float v = tanhf(atom_h[(size_t)srcn[b]*HD + c] + tgt_rel[b*HD + c]
                    - atom_h[(size_t)tgtn[b]*HD + c]);
    float p = v * Wl[c];
    #pragma unroll
    for (int off = 1; off < 64; off <<= 1) p += __shfl_xor(p, off);
    int wv = c >> 6;
    if ((c & 63) == 0) red[wv] = p;
    __syncthreads();
    if (c == 0) out[b] = red[0] + red[1] + red[2] + red[3] + bl[0];
}

extern "C" void kernel_launch(void* const* d_in, const int* in_sizes, int n_in,
                              void* d_out, int out_size, void* d_ws, size_t ws_size,
                              hipStream_t stream)
{
    const float* node_feat = (const float*)d_in[0];
    const float* rel_emb   = (const float*)d_in[1];
    const float* W_i_node  = (const float*)d_in[2];
    const float* W_i_edge  = (const float*)d_in[3];
    const float* Wa1       = (const float*)d_in[4];
    const float* Wa2       = (const float*)d_in[5];
    const float* W_h_atom  = (const float*)d_in[6];
    const float* W_h_bond  = (const float*)d_in[7];
    const float* Wd1       = (const float*)d_in[8];
    const float* Wd2       = (const float*)d_in[9];
    const float* W_comm    = (const float*)d_in[10];
    const float* gru_bias  = (const float*)d_in[11];
    const float* w_ih_f    = (const float*)d_in[12];
    const float* w_hh_f    = (const float*)d_in[13];
    const float* b_ih_f    = (const float*)d_in[14];
    const float* b_hh_f    = (const float*)d_in[15];
    const float* w_ih_b    = (const float*)d_in[16];
    const float* w_hh_b    = (const float*)d_in[17];
    const float* b_ih_b    = (const float*)d_in[18];
    const float* b_hh_b    = (const float*)d_in[19];
    const float* W_o       = (const float*)d_in[20];
    const float* b_o       = (const float*)d_in[21];
    const float* W_lin1    = (const float*)d_in[22];
    const float* b_lin1    = (const float*)d_in[23];
    const int* edge_src  = (const int*)d_in[24];
    const int* edge_dst  = (const int*)d_in[25];
    const int* edge_rel  = (const int*)d_in[26];
    const int* batch_rel = (const int*)d_in[27];
    const int* src_node  = (const int*)d_in[28];
    const int* tgt_node  = (const int*)d_in[29];
    float* out = (float*)d_out;

    float* ws = (float*)d_ws;
    size_t off = 0;
    auto alloc = [&](size_t n){ float* p = ws + off; off += n; return p; };
    float* tgt_rel    = alloc((size_t)Bg*HD);
    float* term       = alloc((size_t)3*Bg*HD);
    float* input_node = alloc((size_t)TNODE*HD);
    float* mn_a       = alloc((size_t)TNODE*HD);
    float* mn_b       = alloc((size_t)TNODE*HD);
    float* agg        = alloc((size_t)TNODE*HD);
    float* h0v        = alloc((size_t)Bg*HD);
    short* whbf       = (short*)alloc((size_t)2*768*256/2);
    float* sbuf       = alloc((size_t)TEDGE);
    int*   cnt        = (int*)alloc((size_t)TNODE);
    int*   fillc      = (int*)alloc((size_t)TNODE);
    int*   rowptr     = (int*)alloc((size_t)TNODE + 256);
    int*   eidx       = (int*)alloc((size_t)TEDGE);
    float* Sbuf       = alloc((size_t)TNODE*HD);
    float* Dbuf       = alloc((size_t)TNODE*HD);
    float* Rbuf       = alloc((size_t)256*HD);
    float* gi_f       = alloc((size_t)TNODE*768);
    float* gi_b       = alloc((size_t)TNODE*768);
    float* out_f      = alloc((size_t)TNODE*HD);
    float* out_b      = alloc((size_t)TNODE*HD);
    // aliases (lifetimes disjoint):
    float* agg2   = mn_a;        // after last attn/gather
    float* atom_h = input_node;  // after W_comm GEMM

    tgtrel_kernel<<<Bg, 256, 0, stream>>>(rel_emb, batch_rel, tgt_rel);
    whbf_kernel<<<1536, 256, 0, stream>>>(w_hh_f, w_hh_b, whbf);

    // ---- CSR build (dst-sorted incidence) ----
    zeroi_kernel<<<2*TNODE/256, 256, 0, stream>>>(cnt);     // zeros cnt AND fillc (adjacent)
    csr_count<<<TEDGE/256, 256, 0, stream>>>(edge_dst, cnt);
    csr_scan<<<1, 256, 0, stream>>>(cnt, rowptr);
    csr_fill<<<TEDGE/256, 256, 0, stream>>>(edge_dst, rowptr, fillc, eidx);

    // input_node = relu(node_feat @ W_i_node^T)
    mgemm<A_PLAIN, E_RELU><<<dim3(HD/128, TNODE/128), 256, 0, stream>>>(
        node_feat, nullptr, nullptr, W_i_node, nullptr, input_node,
        TNODE, HD, NEMB, NEMB, NEMB);

    // edge-feature factor tables: ie[e] = relu(S[src] + R[rel] + D[dst])
    mgemm<A_PLAIN, E_STORE><<<dim3(HD/128, TNODE/128), 256, 0, stream>>>(
        node_feat, nullptr, nullptr, W_i_edge + 0, nullptr, Sbuf,
        TNODE, HD, NEMB, NEMB, 512);
    mgemm<A_PLAIN, E_STORE><<<dim3(HD/128, TNODE/128), 256, 0, stream>>>(
        node_feat, nullptr, nullptr, W_i_edge + 384, nullptr, Dbuf,
        TNODE, HD, NEMB, NEMB, 512);
    mgemm<A_CLAMP, E_STORE><<<dim3(HD/128, 2), 256, 0, stream>>>(
        rel_emb, nullptr, nullptr, W_i_edge + 128, nullptr, Rbuf,
        200, HD, REMB, REMB, 512);

    term_kernel<<<3*Bg, 256, 0, stream>>>(input_node, tgt_rel, Wa1, Wd1,
                                          src_node, tgt_node, term);

    // ---- input attention scale + gather-aggregate ----
    mattn<0><<<TEDGE/64, 256, 0, stream>>>(Sbuf, Rbuf, Dbuf, Sbuf,
        edge_src, edge_rel, edge_dst, Wa1, Wa2, term, sbuf);
    agg_gather<0><<<TNODE/4, 256, 0, stream>>>(Sbuf, Rbuf, Dbuf, Sbuf,
        edge_src, edge_rel, rowptr, eidx, sbuf, agg);

    const float* mn_cur = input_node;
    float* bufs[2] = {mn_a, mn_b};
    for (int d = 0; d < 2; d++) {
        float* mn_next = bufs[d];
        float* tmp     = bufs[1-d];
        mgemm<A_ADD, E_RELU><<<dim3(2, TNODE/128), 256, 0, stream>>>(
            mn_cur, agg, nullptr, W_h_atom + (size_t)d*HD*HD, nullptr, mn_next,
            TNODE, HD, HD, HD, HD);
        mgemm<A_PLAIN, E_STORE><<<dim3(2, TNODE/128), 256, 0, stream>>>(
            mn_next, nullptr, nullptr, W_h_bond + (size_t)d*HD*HD, nullptr, tmp,
            TNODE, HD, HD, HD, HD);
        mattn<1><<<TEDGE/64, 256, 0, stream>>>(Sbuf, Rbuf, Dbuf, tmp,
            edge_src, edge_rel, edge_dst, Wd1 + (size_t)d*HD*512,
            Wd2 + (size_t)d*HD, term + (size_t)(1+d)*Bg*HD, sbuf);
        agg_gather<1><<<TNODE/4, 256, 0, stream>>>(Sbuf, Rbuf, Dbuf, tmp,
            edge_src, edge_rel, rowptr, eidx, sbuf, agg);
        mn_cur = mn_next;
    }

    // agg2 = concat([agg, mn, input_node]) @ W_comm^T   (agg2 aliases mn_a)
    mgemm<A_CAT3, E_STORE><<<dim3(2, TNODE/128), 256, 0, stream>>>(
        agg, (const float*)mn_cur, input_node, W_comm, nullptr, agg2,
        TNODE, HD, 3*HD, 0, 3*HD);

    h0_kernel<<<Bg, 256, 0, stream>>>(agg2, h0v);

    // gi = relu(agg2 + gru_bias) @ w_ih^T + b_ih   (both directions)
    mgemm<A_RELUB, E_BIAS><<<dim3(768/128, TNODE/128), 256, 0, stream>>>(
        agg2, gru_bias, nullptr, w_ih_f, b_ih_f, gi_f,
        TNODE, 768, HD, HD, HD);
    mgemm<A_RELUB, E_BIAS><<<dim3(768/128, TNODE/128), 256, 0, stream>>>(
        agg2, gru_bias, nullptr, w_ih_b, b_ih_b, gi_b,
        TNODE, 768, HD, HD, HD);

    gru_seq<<<16, 1024, 0, stream>>>(gi_f, gi_b, whbf, b_hh_f, b_hh_b, h0v,
                                     out_f, out_b);

    // atom_h = relu(relu(concat(out_f,out_b)) @ W_o^T + b_o)
    mgemm<A_CAT2R, E_BIASRELU><<<dim3(2, TNODE/128), 256, 0, stream>>>(
        out_f, out_b, nullptr, W_o, b_o, atom_h,
        TNODE, HD, 2*HD, 0, 2*HD);

    final_kernel<<<Bg, 256, 0, stream>>>(atom_h, tgt_rel, src_node, tgt_node,
                                         W_lin1, b_lin1, out);
}

// Round 10
// 1510.532 us; speedup vs baseline: 1.9113x; 1.2924x over previous
//
#include <hip/hip_runtime.h>
#include <cstddef>

#define Bg 128
#define Nn 100
#define Eg 800
#define TNODE 12800
#define TEDGE 102400
#define HD 256
#define NEMB 128
#define REMB 256

typedef short bf8 __attribute__((ext_vector_type(8)));
typedef short bf4 __attribute__((ext_vector_type(4)));
typedef float f4  __attribute__((ext_vector_type(4)));

__device__ __forceinline__ float relu_(float x){ return x > 0.f ? x : 0.f; }
__device__ __forceinline__ float sigm_(float x){ return 1.f/(1.f + __expf(-x)); }
__device__ __forceinline__ float4 ld4(const float* p){ return *(const float4*)p; }
__device__ __forceinline__ void st4(float* p, float4 v){ *(float4*)p = v; }
__device__ __forceinline__ float4 add4(float4 a, float4 b){
    return float4{a.x+b.x, a.y+b.y, a.z+b.z, a.w+b.w};
}
__device__ __forceinline__ float4 relu4(float4 a){
    return float4{relu_(a.x), relu_(a.y), relu_(a.z), relu_(a.w)};
}
__device__ __forceinline__ short f2bf(float f){
    unsigned u = __float_as_uint(f);
    u += 0x7fff + ((u >> 16) & 1);
    return (short)(u >> 16);
}
__device__ __forceinline__ float bf2f(short s){
    return __uint_as_float(((unsigned)(unsigned short)s) << 16);
}
__device__ __forceinline__ void split4(float4 v, bf4& h, bf4& l){
    h.x = f2bf(v.x); l.x = f2bf(v.x - bf2f(h.x));
    h.y = f2bf(v.y); l.y = f2bf(v.y - bf2f(h.y));
    h.z = f2bf(v.z); l.z = f2bf(v.z - bf2f(h.z));
    h.w = f2bf(v.w); l.w = f2bf(v.w - bf2f(h.w));
}
__device__ __forceinline__ f4 mfma_(bf8 a, bf8 b, f4 c){
    return __builtin_amdgcn_mfma_f32_16x16x32_bf16(a, b, c, 0, 0, 0);
}

enum { A_PLAIN=0, A_ADD=1, A_RELUB=2, A_CLAMP=3, A_CAT3=4, A_CAT2R=5 };
enum { E_STORE=0, E_RELU=1, E_BIAS=2, E_BIASRELU=3 };

// ---------- MFMA split-bf16 GEMM: C[M,N] = epi(A[M,K] @ W[N,K]^T), ~f32 accuracy ----------
template<int AM, int EM>
__global__ __launch_bounds__(256, 2)
void mgemm(const float* __restrict__ A0, const float* __restrict__ A1,
           const float* __restrict__ A2, const float* __restrict__ W,
           const float* __restrict__ bias, float* __restrict__ C,
           int M, int N, int K, int lda, int wld)
{
    __shared__ short Ah[128][40], Al[128][40], Bh[128][40], Bl[128][40];
    const int t  = threadIdx.x;
    const int kc = t & 7, lr = t >> 3;
    const int lane = t & 63, wv = t >> 6;
    const int wm = wv >> 1, wn = wv & 1;
    const int frow = lane & 15, fk = (lane >> 4) * 8;
    const int row0 = blockIdx.y * 128, col0 = blockIdx.x * 128;

    f4 acc[4][4] = {};

    for (int k0 = 0; k0 < K; k0 += 32) {
        const int gk = k0 + kc * 4;
        const int kk = kc * 4;
        #pragma unroll
        for (int ri = 0; ri < 4; ri++) {
            int row = lr + 32 * ri;
            int grow = row0 + row;
            float4 v;
            if (AM == A_PLAIN) {
                v = ld4(A0 + (size_t)grow * lda + gk);
            } else if (AM == A_ADD) {
                v = add4(ld4(A0 + (size_t)grow * lda + gk),
                         ld4(A1 + (size_t)grow * lda + gk));
            } else if (AM == A_RELUB) {
                v = relu4(add4(ld4(A0 + (size_t)grow * lda + gk), ld4(A1 + gk)));
            } else if (AM == A_CLAMP) {
                int cr = grow < M ? grow : M - 1;
                v = ld4(A0 + (size_t)cr * lda + gk);
            } else if (AM == A_CAT3) {
                if (gk < HD)        v = ld4(A0 + (size_t)grow * HD + gk);
                else if (gk < 2*HD) v = ld4(A1 + (size_t)grow * HD + gk - HD);
                else                v = ld4(A2 + (size_t)grow * HD + gk - 2*HD);
            } else { // A_CAT2R
                v = (gk < HD) ? relu4(ld4(A0 + (size_t)grow * HD + gk))
                              : relu4(ld4(A1 + (size_t)grow * HD + gk - HD));
            }
            bf4 h, l; split4(v, h, l);
            *(bf4*)&Ah[row][kk] = h;
            *(bf4*)&Al[row][kk] = l;
        }
        #pragma unroll
        for (int ri = 0; ri < 4; ri++) {
            int wr = lr + 32 * ri;
            float4 v = ld4(W + (size_t)(col0 + wr) * wld + gk);
            bf4 h, l; split4(v, h, l);
            *(bf4*)&Bh[wr][kk] = h;
            *(bf4*)&Bl[wr][kk] = l;
        }
        __syncthreads();
        bf8 ah[4], al[4], bh[4], bl[4];
        #pragma unroll
        for (int mi = 0; mi < 4; mi++) {
            ah[mi] = *(const bf8*)&Ah[wm*64 + mi*16 + frow][fk];
            al[mi] = *(const bf8*)&Al[wm*64 + mi*16 + frow][fk];
        }
        #pragma unroll
        for (int ni = 0; ni < 4; ni++) {
            bh[ni] = *(const bf8*)&Bh[wn*64 + ni*16 + frow][fk];
            bl[ni] = *(const bf8*)&Bl[wn*64 + ni*16 + frow][fk];
        }
        #pragma unroll
        for (int mi = 0; mi < 4; mi++)
            #pragma unroll
            for (int ni = 0; ni < 4; ni++) {
                acc[mi][ni] = mfma_(ah[mi], bh[ni], acc[mi][ni]);
                acc[mi][ni] = mfma_(ah[mi], bl[ni], acc[mi][ni]);
                acc[mi][ni] = mfma_(al[mi], bh[ni], acc[mi][ni]);
            }
        __syncthreads();
    }
    #pragma unroll
    for (int mi = 0; mi < 4; mi++) {
        #pragma unroll
        for (int ni = 0; ni < 4; ni++) {
            int ccol = col0 + wn*64 + ni*16 + frow;
            int rbase = row0 + wm*64 + mi*16 + (lane >> 4) * 4;
            #pragma unroll
            for (int reg = 0; reg < 4; reg++) {
                float v = acc[mi][ni][reg];
                if (EM == E_BIAS || EM == E_BIASRELU) v += bias[ccol];
                if (EM == E_RELU || EM == E_BIASRELU) v = relu_(v);
                C[(size_t)(rbase + reg) * N + ccol] = v;
            }
        }
    }
}

// ---------- MFMA attention over reconstructed edge features ----------
template<int MODE>
__global__ __launch_bounds__(256, 2)
void mattn(const float* __restrict__ S, const float* __restrict__ Rt,
           const float* __restrict__ D, const float* __restrict__ T0,
           const int* __restrict__ esrc, const int* __restrict__ erel,
           const int* __restrict__ edst,
           const float* __restrict__ W1, const float* __restrict__ W2,
           const float* __restrict__ term, float* __restrict__ sbuf)
{
    __shared__ short Ah[64][40], Al[64][40], Bh[256][40], Bl[256][40];
    __shared__ float partl[4][64];
    __shared__ int isrc[64], irel[64], idst[64];
    const int t = threadIdx.x;
    const int kc = t & 7, lr = t >> 3;
    const int lane = t & 63, wv = t >> 6;
    const int frow = lane & 15, fk = (lane >> 4) * 8;
    const int r0 = blockIdx.x * 64;

    if (t < 64) {
        int e = r0 + t;
        isrc[t] = esrc[e]; irel[t] = erel[e]; idst[t] = edst[e];
    }
    __syncthreads();

    f4 acc[4][4] = {};

    for (int k0 = 0; k0 < HD; k0 += 32) {
        const int gk = k0 + kc * 4;
        const int kk = kc * 4;
        #pragma unroll
        for (int ri = 0; ri < 2; ri++) {
            int row = lr + 32 * ri;
            int s = isrc[row], rl = irel[row], dd = idst[row];
            float4 v = relu4(add4(add4(ld4(S + (size_t)s * HD + gk),
                                       ld4(Rt + (size_t)rl * HD + gk)),
                                  ld4(D + (size_t)dd * HD + gk)));
            if (MODE) v = relu4(add4(v, ld4(T0 + (size_t)s * HD + gk)));
            bf4 h, l; split4(v, h, l);
            *(bf4*)&Ah[row][kk] = h;
            *(bf4*)&Al[row][kk] = l;
        }
        #pragma unroll
        for (int ri = 0; ri < 8; ri++) {
            int wr = lr + 32 * ri;
            float4 v = ld4(W1 + (size_t)wr * 512 + gk);   // left half of [256,512]
            bf4 h, l; split4(v, h, l);
            *(bf4*)&Bh[wr][kk] = h;
            *(bf4*)&Bl[wr][kk] = l;
        }
        __syncthreads();
        bf8 ah[4], al[4], bh[4], bl[4];
        #pragma unroll
        for (int mi = 0; mi < 4; mi++) {
            ah[mi] = *(const bf8*)&Ah[mi*16 + frow][fk];
            al[mi] = *(const bf8*)&Al[mi*16 + frow][fk];
        }
        #pragma unroll
        for (int ni = 0; ni < 4; ni++) {
            bh[ni] = *(const bf8*)&Bh[wv*64 + ni*16 + frow][fk];
            bl[ni] = *(const bf8*)&Bl[wv*64 + ni*16 + frow][fk];
        }
        #pragma unroll
        for (int mi = 0; mi < 4; mi++)
            #pragma unroll
            for (int ni = 0; ni < 4; ni++) {
                acc[mi][ni] = mfma_(ah[mi], bh[ni], acc[mi][ni]);
                acc[mi][ni] = mfma_(ah[mi], bl[ni], acc[mi][ni]);
                acc[mi][ni] = mfma_(al[mi], bh[ni], acc[mi][ni]);
            }
        __syncthreads();
    }
    #pragma unroll
    for (int mi = 0; mi < 4; mi++) {
        #pragma unroll
        for (int reg = 0; reg < 4; reg++) {
            int rl = mi*16 + (lane >> 4) * 4 + reg;
            int g = (r0 + rl) / Eg;
            float p = 0.f;
            #pragma unroll
            for (int ni = 0; ni < 4; ni++) {
                int n = wv*64 + ni*16 + frow;
                p += tanhf(acc[mi][ni][reg] + term[g*HD + n]) * W2[n];
            }
            p += __shfl_xor(p, 1); p += __shfl_xor(p, 2);
            p += __shfl_xor(p, 4); p += __shfl_xor(p, 8);
            if (frow == 0) partl[wv][rl] = p;
        }
    }
    __syncthreads();
    if (t < 64) {
        float p = partl[0][t] + partl[1][t] + partl[2][t] + partl[3][t];
        sbuf[r0 + t] = sigm_(p);
    }
}

// ------- CSR-gather aggregation: agg[n] = sum_{e: dst[e]==n} me(e) * s[e] -------
template<int MODE>
__global__ __launch_bounds__(256)
void agg_gather(const float* __restrict__ S, const float* __restrict__ Rt,
                const float* __restrict__ D, const float* __restrict__ T0,
                const int* __restrict__ esrc, const int* __restrict__ erel,
                const int* __restrict__ rowptr, const int* __restrict__ eidx,
                const float* __restrict__ s, float* __restrict__ agg)
{
    int node = blockIdx.x * 4 + (threadIdx.x >> 6);
    int c = (threadIdx.x & 63) * 4;
    float4 dn = ld4(D + (size_t)node * HD + c);   // dst row constant per node
    float4 acc{0.f, 0.f, 0.f, 0.f};
    int beg = rowptr[node], end = rowptr[node + 1];
    for (int i = beg; i < end; i++) {
        int e = eidx[i];
        int sr = esrc[e], rl = erel[e];
        float4 v = relu4(add4(add4(ld4(S + (size_t)sr * HD + c),
                                   ld4(Rt + (size_t)rl * HD + c)), dn));
        if (MODE) v = relu4(add4(v, ld4(T0 + (size_t)sr * HD + c)));
        float sc = s[e];
        acc.x += v.x * sc; acc.y += v.y * sc;
        acc.z += v.z * sc; acc.w += v.w * sc;
    }
    st4(agg + (size_t)node * HD + c, acc);
}

// ------------- CSR build -------------
__global__ void zeroi_kernel(int* __restrict__ p)
{
    p[blockIdx.x * 256 + threadIdx.x] = 0;
}
__global__ void csr_count(const int* __restrict__ dst, int* __restrict__ cnt)
{
    int e = blockIdx.x * 256 + threadIdx.x;
    atomicAdd(&cnt[dst[e]], 1);
}
__global__ void csr_scan(const int* __restrict__ cnt, int* __restrict__ rowptr)
{
    __shared__ int ws[4];
    __shared__ int carry;
    int tid = threadIdx.x;
    if (tid == 0) carry = 0;
    __syncthreads();
    for (int i = 0; i < TNODE; i += 256) {
        int v = cnt[i + tid];
        int x = v;
        #pragma unroll
        for (int off = 1; off < 64; off <<= 1) {
            int y = __shfl_up(x, off);
            if ((tid & 63) >= off) x += y;
        }
        if ((tid & 63) == 63) ws[tid >> 6] = x;
        __syncthreads();
        int add = carry;
        int w = tid >> 6;
        for (int j = 0; j < w; j++) add += ws[j];
        rowptr[i + tid] = add + x - v;      // exclusive
        __syncthreads();
        if (tid == 255) carry = add + x;
        __syncthreads();
    }
    if (tid == 0) rowptr[TNODE] = carry;
}
__global__ void csr_fill(const int* __restrict__ dst, const int* __restrict__ rowptr,
                         int* __restrict__ fillc, int* __restrict__ eidx)
{
    int e = blockIdx.x * 256 + threadIdx.x;
    int d = dst[e];
    int slot = rowptr[d] + atomicAdd(&fillc[d], 1);
    eidx[slot] = e;
}

// ------------- per-graph attention bias terms -------------
__global__ __launch_bounds__(256)
void term_kernel(const float* __restrict__ mn, const float* __restrict__ tgt_rel,
                 const float* __restrict__ Wa1, const float* __restrict__ Wd1,
                 const int* __restrict__ srcn, const int* __restrict__ tgtn,
                 float* __restrict__ term)
{
    __shared__ float Gs[HD];
    int b = blockIdx.x % Bg;
    int which = blockIdx.x / Bg;
    int c = threadIdx.x;
    float g;
    if (which == 0)
        g = mn[(size_t)srcn[b]*HD + c] + tgt_rel[b*HD + c] - mn[(size_t)tgtn[b]*HD + c];
    else
        g = tgt_rel[b*HD + c];
    Gs[c] = g;
    __syncthreads();
    const float* W = (which == 0) ? Wa1 : (Wd1 + (size_t)(which-1)*HD*512);
    float p = 0.f;
    for (int k = 0; k < HD; k += 4) {
        float4 w = ld4(W + (size_t)c*512 + 256 + k);
        p = fmaf(Gs[k], w.x, p); p = fmaf(Gs[k+1], w.y, p);
        p = fmaf(Gs[k+2], w.z, p); p = fmaf(Gs[k+3], w.w, p);
    }
    term[(size_t)which*Bg*HD + b*HD + c] = p;
}

__global__ void tgtrel_kernel(const float* __restrict__ rel_emb, const int* __restrict__ batch_rel,
                              float* __restrict__ tgt_rel)
{
    int b = blockIdx.x, c = threadIdx.x;
    tgt_rel[b*HD + c] = rel_emb[(size_t)batch_rel[b]*REMB + c];
}

__global__ void h0_kernel(const float* __restrict__ agg2, float* __restrict__ h0)
{
    int b = blockIdx.x, c = threadIdx.x;
    float m = -1e30f;
    for (int n = 0; n < Nn; n++)
        m = fmaxf(m, agg2[((size_t)b*Nn + n)*HD + c]);
    h0[b*HD + c] = m;
}

// ------------- convert w_hh to bf16: whbf[d][row][k] -------------
__global__ void whbf_kernel(const float* __restrict__ whf, const float* __restrict__ whb,
                            short* __restrict__ whbf)
{
    int idx = blockIdx.x * 256 + threadIdx.x;   // 2*768*256
    int d = idx / (768*256), rem = idx % (768*256);
    whbf[idx] = f2bf((d ? whb : whf)[rem]);
}

// ------------- GRU: 16 blocks = (dir, grp of 16 seqs); block-local recurrence -------------
// h kept in LDS as f32 + pre-split bf16 hi/lo (split ONCE per step in epilogue, not per wave).
// MFMA phase: A frags via ds_read, weights streamed from L2. gi prefetched before barrier.
__global__ __launch_bounds__(1024)
void gru_seq(const float* __restrict__ gi_f, const float* __restrict__ gi_b,
             const short* __restrict__ whbf,
             const float* __restrict__ bhf, const float* __restrict__ bhb,
             const float* __restrict__ h0,
             float* __restrict__ outf, float* __restrict__ outb)
{
    __shared__ float hsf[16][260];      // h state f32 (epilogue hprev)
    __shared__ short hsh[16][264];      // h bf16 hi
    __shared__ short hsl[16][264];      // h bf16 lo
    __shared__ float gates[768][17];    // [gate*256+h][seq]
    const int blk = blockIdx.x;         // dir*8 + grp
    const int d = blk >> 3, grp = blk & 7;
    const int tid = threadIdx.x;
    const int lane = tid & 63, wv = tid >> 6;   // 16 waves
    const int f16 = lane & 15;          // A row (seq) / B row within tile
    const int kb  = (lane >> 4) * 8;    // k sub-offset

    const short* wp0 = whbf + (size_t)d * 768 * 256;
    const float* gi  = d ? gi_b : gi_f;
    const float* bh  = d ? bhb : bhf;
    float* outp      = d ? outb : outf;

    const int eseq = tid >> 6, ehb = tid & 63;      // epilogue ownership
    float bhr[4], bhz[4], bhn[4];
    #pragma unroll
    for (int hh = 0; hh < 4; hh++) {
        int h = ehb + hh * 64;
        bhr[hh] = bh[h]; bhz[hh] = bh[256 + h]; bhn[hh] = bh[512 + h];
    }

    {   // init h: f32 + hi/lo split (each thread owns 4 (seq,h))
        #pragma unroll
        for (int hh = 0; hh < 4; hh++) {
            int h = ehb + hh * 64;
            float v = h0[(size_t)(grp*16 + eseq) * HD + h];
            hsf[eseq][h] = v;
            short hi = f2bf(v);
            hsh[eseq][h] = hi;
            hsl[eseq][h] = f2bf(v - bf2f(hi));
        }
    }
    __syncthreads();

    for (int t = 0; t < Nn; t++) {
        int trow = d ? (Nn - 1 - t) : t;
        // --- gi prefetch (independent of gates; hides HBM latency under MFMA) ---
        float gr[4], gz[4], gn[4];
        {
            size_t girow = ((size_t)(grp*16 + eseq) * Nn + trow) * 768;
            #pragma unroll
            for (int hh = 0; hh < 4; hh++) {
                int h = ehb + hh * 64;
                gr[hh] = gi[girow + h];
                gz[hh] = gi[girow + 256 + h];
                gn[hh] = gi[girow + 512 + h];
            }
        }
        // --- 3 n-tiles per wave: A frags from LDS (pre-split), B streamed from L2 ---
        #pragma unroll
        for (int j = 0; j < 3; j++) {
            int wr = (wv*3 + j) * 16 + f16;
            const short* wp = wp0 + (size_t)wr * 256 + kb;
            f4 acc = {};
            #pragma unroll
            for (int ks = 0; ks < 8; ks++) {
                bf8 ahi = *(const bf8*)&hsh[f16][ks*32 + kb];
                bf8 alo = *(const bf8*)&hsl[f16][ks*32 + kb];
                bf8 b = *(const bf8*)(wp + ks*32);
                acc = mfma_(ahi, b, acc);
                acc = mfma_(alo, b, acc);
            }
            #pragma unroll
            for (int reg = 0; reg < 4; reg++)
                gates[(wv*3 + j)*16 + f16][(lane >> 4)*4 + reg] = acc[reg];
        }
        __syncthreads();
        // --- epilogue: thread owns (eseq, ehb+hh*64) ---
        {
            size_t orow = ((size_t)(grp*16 + eseq) * Nn + trow) * HD;
            #pragma unroll
            for (int hh = 0; hh < 4; hh++) {
                int h = ehb + hh * 64;
                float R  = gates[h][eseq];
                float Z  = gates[256 + h][eseq];
                float NN = gates[512 + h][eseq];
                float hprev = hsf[eseq][h];
                float r = sigm_(gr[hh] + R + bhr[hh]);
                float z = sigm_(gz[hh] + Z + bhz[hh]);
                float n = tanhf(gn[hh] + r * (NN + bhn[hh]));
                float nh = (1.f - z) * n + z * hprev;
                hsf[eseq][h] = nh;
                short hi = f2bf(nh);
                hsh[eseq][h] = hi;
                hsl[eseq][h] = f2bf(nh - bf2f(hi));
                outp[orow + h] = nh;
            }
        }
        __syncthreads();
    }
}

__global__ __launch_bounds__(256)
void final_kernel(const float* __restrict__ atom_h, const float* __restrict__ tgt_rel,
                  const int* __restrict__ srcn, const int* __restrict__ tgtn,
                  const float* __restrict__ Wl, const float* __restrict__ bl,
                  float* __restrict__ out)
{
    __shared__ float red[4];
    int b = blockIdx.x, c = threadIdx.x;
    float v = tanhf(atom_h[(size_t)srcn[b]*HD + c] + tgt_rel[b*HD + c]
                    - atom_h[(size_t)tgtn[b]*HD + c]);
    float p = v * Wl[c];
    #pragma unroll
    for (int off = 1; off < 64; off <<= 1) p += __shfl_xor(p, off);
    int wv = c >> 6;
    if ((c & 63) == 0) red[wv] = p;
    __syncthreads();
    if (c == 0) out[b] = red[0] + red[1] + red[2] + red[3] + bl[0];
}

extern "C" void kernel_launch(void* const* d_in, const int* in_sizes, int n_in,
                              void* d_out, int out_size, void* d_ws, size_t ws_size,
                              hipStream_t stream)
{
    const float* node_feat = (const float*)d_in[0];
    const float* rel_emb   = (const float*)d_in[1];
    const float* W_i_node  = (const float*)d_in[2];
    const float* W_i_edge  = (const float*)d_in[3];
    const float* Wa1       = (const float*)d_in[4];
    const float* Wa2       = (const float*)d_in[5];
    const float* W_h_atom  = (const float*)d_in[6];
    const float* W_h_bond  = (const float*)d_in[7];
    const float* Wd1       = (const float*)d_in[8];
    const float* Wd2       = (const float*)d_in[9];
    const float* W_comm    = (const float*)d_in[10];
    const float* gru_bias  = (const float*)d_in[11];
    const float* w_ih_f    = (const float*)d_in[12];
    const float* w_hh_f    = (const float*)d_in[13];
    const float* b_ih_f    = (const float*)d_in[14];
    const float* b_hh_f    = (const float*)d_in[15];
    const float* w_ih_b    = (const float*)d_in[16];
    const float* w_hh_b    = (const float*)d_in[17];
    const float* b_ih_b    = (const float*)d_in[18];
    const float* b_hh_b    = (const float*)d_in[19];
    const float* W_o       = (const float*)d_in[20];
    const float* b_o       = (const float*)d_in[21];
    const float* W_lin1    = (const float*)d_in[22];
    const float* b_lin1    = (const float*)d_in[23];
    const int* edge_src  = (const int*)d_in[24];
    const int* edge_dst  = (const int*)d_in[25];
    const int* edge_rel  = (const int*)d_in[26];
    const int* batch_rel = (const int*)d_in[27];
    const int* src_node  = (const int*)d_in[28];
    const int* tgt_node  = (const int*)d_in[29];
    float* out = (float*)d_out;

    float* ws = (float*)d_ws;
    size_t off = 0;
    auto alloc = [&](size_t n){ float* p = ws + off; off += n; return p; };
    float* tgt_rel    = alloc((size_t)Bg*HD);
    float* term       = alloc((size_t)3*Bg*HD);
    float* input_node = alloc((size_t)TNODE*HD);
    float* mn_a       = alloc((size_t)TNODE*HD);
    float* mn_b       = alloc((size_t)TNODE*HD);
    float* agg        = alloc((size_t)TNODE*HD);
    float* h0v        = alloc((size_t)Bg*HD);
    short* whbf       = (short*)alloc((size_t)2*768*256/2);
    float* sbuf       = alloc((size_t)TEDGE);
    int*   cnt        = (int*)alloc((size_t)TNODE);
    int*   fillc      = (int*)alloc((size_t)TNODE);
    int*   rowptr     = (int*)alloc((size_t)TNODE + 256);
    int*   eidx       = (int*)alloc((size_t)TEDGE);
    float* Sbuf       = alloc((size_t)TNODE*HD);
    float* Dbuf       = alloc((size_t)TNODE*HD);
    float* Rbuf       = alloc((size_t)256*HD);
    float* gi_f       = alloc((size_t)TNODE*768);
    float* gi_b       = alloc((size_t)TNODE*768);
    float* out_f      = alloc((size_t)TNODE*HD);
    float* out_b      = alloc((size_t)TNODE*HD);
    // aliases (lifetimes disjoint):
    float* agg2   = mn_a;        // after last attn/gather
    float* atom_h = input_node;  // after W_comm GEMM

    tgtrel_kernel<<<Bg, 256, 0, stream>>>(rel_emb, batch_rel, tgt_rel);
    whbf_kernel<<<1536, 256, 0, stream>>>(w_hh_f, w_hh_b, whbf);

    // ---- CSR build (dst-sorted incidence) ----
    zeroi_kernel<<<2*TNODE/256, 256, 0, stream>>>(cnt);     // zeros cnt AND fillc (adjacent)
    csr_count<<<TEDGE/256, 256, 0, stream>>>(edge_dst, cnt);
    csr_scan<<<1, 256, 0, stream>>>(cnt, rowptr);
    csr_fill<<<TEDGE/256, 256, 0, stream>>>(edge_dst, rowptr, fillc, eidx);

    // input_node = relu(node_feat @ W_i_node^T)
    mgemm<A_PLAIN, E_RELU><<<dim3(HD/128, TNODE/128), 256, 0, stream>>>(
        node_feat, nullptr, nullptr, W_i_node, nullptr, input_node,
        TNODE, HD, NEMB, NEMB, NEMB);

    // edge-feature factor tables: ie[e] = relu(S[src] + R[rel] + D[dst])
    mgemm<A_PLAIN, E_STORE><<<dim3(HD/128, TNODE/128), 256, 0, stream>>>(
        node_feat, nullptr, nullptr, W_i_edge + 0, nullptr, Sbuf,
        TNODE, HD, NEMB, NEMB, 512);
    mgemm<A_PLAIN, E_STORE><<<dim3(HD/128, TNODE/128), 256, 0, stream>>>(
        node_feat, nullptr, nullptr, W_i_edge + 384, nullptr, Dbuf,
        TNODE, HD, NEMB, NEMB, 512);
    mgemm<A_CLAMP, E_STORE><<<dim3(HD/128, 2), 256, 0, stream>>>(
        rel_emb, nullptr, nullptr, W_i_edge + 128, nullptr, Rbuf,
        200, HD, REMB, REMB, 512);

    term_kernel<<<3*Bg, 256, 0, stream>>>(input_node, tgt_rel, Wa1, Wd1,
                                          src_node, tgt_node, term);

    // ---- input attention scale + gather-aggregate ----
    mattn<0><<<TEDGE/64, 256, 0, stream>>>(Sbuf, Rbuf, Dbuf, Sbuf,
        edge_src, edge_rel, edge_dst, Wa1, Wa2, term, sbuf);
    agg_gather<0><<<TNODE/4, 256, 0, stream>>>(Sbuf, Rbuf, Dbuf, Sbuf,
        edge_src, edge_rel, rowptr, eidx, sbuf, agg);

    const float* mn_cur = input_node;
    float* bufs[2] = {mn_a, mn_b};
    for (int d = 0; d < 2; d++) {
        float* mn_next = bufs[d];
        float* tmp     = bufs[1-d];
        mgemm<A_ADD, E_RELU><<<dim3(2, TNODE/128), 256, 0, stream>>>(
            mn_cur, agg, nullptr, W_h_atom + (size_t)d*HD*HD, nullptr, mn_next,
            TNODE, HD, HD, HD, HD);
        mgemm<A_PLAIN, E_STORE><<<dim3(2, TNODE/128), 256, 0, stream>>>(
            mn_next, nullptr, nullptr, W_h_bond + (size_t)d*HD*HD, nullptr, tmp,
            TNODE, HD, HD, HD, HD);
        mattn<1><<<TEDGE/64, 256, 0, stream>>>(Sbuf, Rbuf, Dbuf, tmp,
            edge_src, edge_rel, edge_dst, Wd1 + (size_t)d*HD*512,
            Wd2 + (size_t)d*HD, term + (size_t)(1+d)*Bg*HD, sbuf);
        agg_gather<1><<<TNODE/4, 256, 0, stream>>>(Sbuf, Rbuf, Dbuf, tmp,
            edge_src, edge_rel, rowptr, eidx, sbuf, agg);
        mn_cur = mn_next;
    }

    // agg2 = concat([agg, mn, input_node]) @ W_comm^T   (agg2 aliases mn_a)
    mgemm<A_CAT3, E_STORE><<<dim3(2, TNODE/128), 256, 0, stream>>>(
        agg, (const float*)mn_cur, input_node, W_comm, nullptr, agg2,
        TNODE, HD, 3*HD, 0, 3*HD);

    h0_kernel<<<Bg, 256, 0, stream>>>(agg2, h0v);

    // gi = relu(agg2 + gru_bias) @ w_ih^T + b_ih   (both directions)
    mgemm<A_RELUB, E_BIAS><<<dim3(768/128, TNODE/128), 256, 0, stream>>>(
        agg2, gru_bias, nullptr, w_ih_f, b_ih_f, gi_f,
        TNODE, 768, HD, HD, HD);
    mgemm<A_RELUB, E_BIAS><<<dim3(768/128, TNODE/128), 256, 0, stream>>>(
        agg2, gru_bias, nullptr, w_ih_b, b_ih_b, gi_b,
        TNODE, 768, HD, HD, HD);

    gru_seq<<<16, 1024, 0, stream>>>(gi_f, gi_b, whbf, b_hh_f, b_hh_b, h0v,
                                     out_f, out_b);

    // atom_h = relu(relu(concat(out_f,out_b)) @ W_o^T + b_o)
    mgemm<A_CAT2R, E_BIASRELU><<<dim3(2, TNODE/128), 256, 0, stream>>>(
        out_f, out_b, nullptr, W_o, b_o, atom_h,
        TNODE, HD, 2*HD, 0, 2*HD);

    final_kernel<<<Bg, 256, 0, stream>>>(atom_h, tgt_rel, src_node, tgt_node,
                                         W_lin1, b_lin1, out);
}

// Round 11
// 1477.631 us; speedup vs baseline: 1.9539x; 1.0223x over previous
//
#include <hip/hip_runtime.h>
#include <cstddef>

#define Bg 128
#define Nn 100
#define Eg 800
#define TNODE 12800
#define TEDGE 102400
#define HD 256
#define NEMB 128
#define REMB 256

typedef short bf8 __attribute__((ext_vector_type(8)));
typedef short bf4 __attribute__((ext_vector_type(4)));
typedef float f4  __attribute__((ext_vector_type(4)));

__device__ __forceinline__ float relu_(float x){ return x > 0.f ? x : 0.f; }
__device__ __forceinline__ float sigm_(float x){ return 1.f/(1.f + __expf(-x)); }
__device__ __forceinline__ float4 ld4(const float* p){ return *(const float4*)p; }
__device__ __forceinline__ void st4(float* p, float4 v){ *(float4*)p = v; }
__device__ __forceinline__ float4 add4(float4 a, float4 b){
    return float4{a.x+b.x, a.y+b.y, a.z+b.z, a.w+b.w};
}
__device__ __forceinline__ float4 relu4(float4 a){
    return float4{relu_(a.x), relu_(a.y), relu_(a.z), relu_(a.w)};
}
__device__ __forceinline__ short f2bf(float f){
    unsigned u = __float_as_uint(f);
    u += 0x7fff + ((u >> 16) & 1);
    return (short)(u >> 16);
}
__device__ __forceinline__ float bf2f(short s){
    return __uint_as_float(((unsigned)(unsigned short)s) << 16);
}
__device__ __forceinline__ void split4(float4 v, bf4& h, bf4& l){
    h.x = f2bf(v.x); l.x = f2bf(v.x - bf2f(h.x));
    h.y = f2bf(v.y); l.y = f2bf(v.y - bf2f(h.y));
    h.z = f2bf(v.z); l.z = f2bf(v.z - bf2f(h.z));
    h.w = f2bf(v.w); l.w = f2bf(v.w - bf2f(h.w));
}
__device__ __forceinline__ f4 mfma_(bf8 a, bf8 b, f4 c){
    return __builtin_amdgcn_mfma_f32_16x16x32_bf16(a, b, c, 0, 0, 0);
}

enum { A_PLAIN=0, A_ADD=1, A_RELUB=2, A_CLAMP=3, A_CAT3=4, A_CAT2R=5 };
enum { E_STORE=0, E_RELU=1, E_BIAS=2, E_BIASRELU=3 };

// ---------- MFMA split-bf16 GEMM: C[M,N] = epi(A[M,K] @ W[N,K]^T), ~f32 accuracy ----------
template<int AM, int EM>
__global__ __launch_bounds__(256, 2)
void mgemm(const float* __restrict__ A0, const float* __restrict__ A1,
           const float* __restrict__ A2, const float* __restrict__ W,
           const float* __restrict__ bias, float* __restrict__ C,
           int M, int N, int K, int lda, int wld)
{
    __shared__ short Ah[128][40], Al[128][40], Bh[128][40], Bl[128][40];
    const int t  = threadIdx.x;
    const int kc = t & 7, lr = t >> 3;
    const int lane = t & 63, wv = t >> 6;
    const int wm = wv >> 1, wn = wv & 1;
    const int frow = lane & 15, fk = (lane >> 4) * 8;
    const int row0 = blockIdx.y * 128, col0 = blockIdx.x * 128;

    f4 acc[4][4] = {};

    for (int k0 = 0; k0 < K; k0 += 32) {
        const int gk = k0 + kc * 4;
        const int kk = kc * 4;
        #pragma unroll
        for (int ri = 0; ri < 4; ri++) {
            int row = lr + 32 * ri;
            int grow = row0 + row;
            float4 v;
            if (AM == A_PLAIN) {
                v = ld4(A0 + (size_t)grow * lda + gk);
            } else if (AM == A_ADD) {
                v = add4(ld4(A0 + (size_t)grow * lda + gk),
                         ld4(A1 + (size_t)grow * lda + gk));
            } else if (AM == A_RELUB) {
                v = relu4(add4(ld4(A0 + (size_t)grow * lda + gk), ld4(A1 + gk)));
            } else if (AM == A_CLAMP) {
                int cr = grow < M ? grow : M - 1;
                v = ld4(A0 + (size_t)cr * lda + gk);
            } else if (AM == A_CAT3) {
                if (gk < HD)        v = ld4(A0 + (size_t)grow * HD + gk);
                else if (gk < 2*HD) v = ld4(A1 + (size_t)grow * HD + gk - HD);
                else                v = ld4(A2 + (size_t)grow * HD + gk - 2*HD);
            } else { // A_CAT2R
                v = (gk < HD) ? relu4(ld4(A0 + (size_t)grow * HD + gk))
                              : relu4(ld4(A1 + (size_t)grow * HD + gk - HD));
            }
            bf4 h, l; split4(v, h, l);
            *(bf4*)&Ah[row][kk] = h;
            *(bf4*)&Al[row][kk] = l;
        }
        #pragma unroll
        for (int ri = 0; ri < 4; ri++) {
            int wr = lr + 32 * ri;
            float4 v = ld4(W + (size_t)(col0 + wr) * wld + gk);
            bf4 h, l; split4(v, h, l);
            *(bf4*)&Bh[wr][kk] = h;
            *(bf4*)&Bl[wr][kk] = l;
        }
        __syncthreads();
        bf8 ah[4], al[4], bh[4], bl[4];
        #pragma unroll
        for (int mi = 0; mi < 4; mi++) {
            ah[mi] = *(const bf8*)&Ah[wm*64 + mi*16 + frow][fk];
            al[mi] = *(const bf8*)&Al[wm*64 + mi*16 + frow][fk];
        }
        #pragma unroll
        for (int ni = 0; ni < 4; ni++) {
            bh[ni] = *(const bf8*)&Bh[wn*64 + ni*16 + frow][fk];
            bl[ni] = *(const bf8*)&Bl[wn*64 + ni*16 + frow][fk];
        }
        #pragma unroll
        for (int mi = 0; mi < 4; mi++)
            #pragma unroll
            for (int ni = 0; ni < 4; ni++) {
                acc[mi][ni] = mfma_(ah[mi], bh[ni], acc[mi][ni]);
                acc[mi][ni] = mfma_(ah[mi], bl[ni], acc[mi][ni]);
                acc[mi][ni] = mfma_(al[mi], bh[ni], acc[mi][ni]);
            }
        __syncthreads();
    }
    #pragma unroll
    for (int mi = 0; mi < 4; mi++) {
        #pragma unroll
        for (int ni = 0; ni < 4; ni++) {
            int ccol = col0 + wn*64 + ni*16 + frow;
            int rbase = row0 + wm*64 + mi*16 + (lane >> 4) * 4;
            #pragma unroll
            for (int reg = 0; reg < 4; reg++) {
                float v = acc[mi][ni][reg];
                if (EM == E_BIAS || EM == E_BIASRELU) v += bias[ccol];
                if (EM == E_RELU || EM == E_BIASRELU) v = relu_(v);
                C[(size_t)(rbase + reg) * N + ccol] = v;
            }
        }
    }
}

// ---------- MFMA attention over reconstructed edge features ----------
template<int MODE>
__global__ __launch_bounds__(256, 2)
void mattn(const float* __restrict__ S, const float* __restrict__ Rt,
           const float* __restrict__ D, const float* __restrict__ T0,
           const int* __restrict__ esrc, const int* __restrict__ erel,
           const int* __restrict__ edst,
           const float* __restrict__ W1, const float* __restrict__ W2,
           const float* __restrict__ term, float* __restrict__ sbuf)
{
    __shared__ short Ah[64][40], Al[64][40], Bh[256][40], Bl[256][40];
    __shared__ float partl[4][64];
    __shared__ int isrc[64], irel[64], idst[64];
    const int t = threadIdx.x;
    const int kc = t & 7, lr = t >> 3;
    const int lane = t & 63, wv = t >> 6;
    const int frow = lane & 15, fk = (lane >> 4) * 8;
    const int r0 = blockIdx.x * 64;

    if (t < 64) {
        int e = r0 + t;
        isrc[t] = esrc[e]; irel[t] = erel[e]; idst[t] = edst[e];
    }
    __syncthreads();

    f4 acc[4][4] = {};

    for (int k0 = 0; k0 < HD; k0 += 32) {
        const int gk = k0 + kc * 4;
        const int kk = kc * 4;
        #pragma unroll
        for (int ri = 0; ri < 2; ri++) {
            int row = lr + 32 * ri;
            int s = isrc[row], rl = irel[row], dd = idst[row];
            float4 v = relu4(add4(add4(ld4(S + (size_t)s * HD + gk),
                                       ld4(Rt + (size_t)rl * HD + gk)),
                                  ld4(D + (size_t)dd * HD + gk)));
            if (MODE) v = relu4(add4(v, ld4(T0 + (size_t)s * HD + gk)));
            bf4 h, l; split4(v, h, l);
            *(bf4*)&Ah[row][kk] = h;
            *(bf4*)&Al[row][kk] = l;
        }
        #pragma unroll
        for (int ri = 0; ri < 8; ri++) {
            int wr = lr + 32 * ri;
            float4 v = ld4(W1 + (size_t)wr * 512 + gk);   // left half of [256,512]
            bf4 h, l; split4(v, h, l);
            *(bf4*)&Bh[wr][kk] = h;
            *(bf4*)&Bl[wr][kk] = l;
        }
        __syncthreads();
        bf8 ah[4], al[4], bh[4], bl[4];
        #pragma unroll
        for (int mi = 0; mi < 4; mi++) {
            ah[mi] = *(const bf8*)&Ah[mi*16 + frow][fk];
            al[mi] = *(const bf8*)&Al[mi*16 + frow][fk];
        }
        #pragma unroll
        for (int ni = 0; ni < 4; ni++) {
            bh[ni] = *(const bf8*)&Bh[wv*64 + ni*16 + frow][fk];
            bl[ni] = *(const bf8*)&Bl[wv*64 + ni*16 + frow][fk];
        }
        #pragma unroll
        for (int mi = 0; mi < 4; mi++)
            #pragma unroll
            for (int ni = 0; ni < 4; ni++) {
                acc[mi][ni] = mfma_(ah[mi], bh[ni], acc[mi][ni]);
                acc[mi][ni] = mfma_(ah[mi], bl[ni], acc[mi][ni]);
                acc[mi][ni] = mfma_(al[mi], bh[ni], acc[mi][ni]);
            }
        __syncthreads();
    }
    #pragma unroll
    for (int mi = 0; mi < 4; mi++) {
        #pragma unroll
        for (int reg = 0; reg < 4; reg++) {
            int rl = mi*16 + (lane >> 4) * 4 + reg;
            int g = (r0 + rl) / Eg;
            float p = 0.f;
            #pragma unroll
            for (int ni = 0; ni < 4; ni++) {
                int n = wv*64 + ni*16 + frow;
                p += tanhf(acc[mi][ni][reg] + term[g*HD + n]) * W2[n];
            }
            p += __shfl_xor(p, 1); p += __shfl_xor(p, 2);
            p += __shfl_xor(p, 4); p += __shfl_xor(p, 8);
            if (frow == 0) partl[wv][rl] = p;
        }
    }
    __syncthreads();
    if (t < 64) {
        float p = partl[0][t] + partl[1][t] + partl[2][t] + partl[3][t];
        sbuf[r0 + t] = sigm_(p);
    }
}

// ------- CSR-gather aggregation: agg[n] = sum_{e: dst[e]==n} me(e) * s[e] -------
template<int MODE>
__global__ __launch_bounds__(256)
void agg_gather(const float* __restrict__ S, const float* __restrict__ Rt,
                const float* __restrict__ D, const float* __restrict__ T0,
                const int* __restrict__ esrc, const int* __restrict__ erel,
                const int* __restrict__ rowptr, const int* __restrict__ eidx,
                const float* __restrict__ s, float* __restrict__ agg)
{
    int node = blockIdx.x * 4 + (threadIdx.x >> 6);
    int c = (threadIdx.x & 63) * 4;
    float4 dn = ld4(D + (size_t)node * HD + c);   // dst row constant per node
    float4 acc{0.f, 0.f, 0.f, 0.f};
    int beg = rowptr[node], end = rowptr[node + 1];
    for (int i = beg; i < end; i++) {
        int e = eidx[i];
        int sr = esrc[e], rl = erel[e];
        float4 v = relu4(add4(add4(ld4(S + (size_t)sr * HD + c),
                                   ld4(Rt + (size_t)rl * HD + c)), dn));
        if (MODE) v = relu4(add4(v, ld4(T0 + (size_t)sr * HD + c)));
        float sc = s[e];
        acc.x += v.x * sc; acc.y += v.y * sc;
        acc.z += v.z * sc; acc.w += v.w * sc;
    }
    st4(agg + (size_t)node * HD + c, acc);
}

// ------------- CSR build -------------
__global__ void zeroi_kernel(int* __restrict__ p)
{
    p[blockIdx.x * 256 + threadIdx.x] = 0;
}
__global__ void csr_count(const int* __restrict__ dst, int* __restrict__ cnt)
{
    int e = blockIdx.x * 256 + threadIdx.x;
    atomicAdd(&cnt[dst[e]], 1);
}
__global__ void csr_scan(const int* __restrict__ cnt, int* __restrict__ rowptr)
{
    __shared__ int ws[4];
    __shared__ int carry;
    int tid = threadIdx.x;
    if (tid == 0) carry = 0;
    __syncthreads();
    for (int i = 0; i < TNODE; i += 256) {
        int v = cnt[i + tid];
        int x = v;
        #pragma unroll
        for (int off = 1; off < 64; off <<= 1) {
            int y = __shfl_up(x, off);
            if ((tid & 63) >= off) x += y;
        }
        if ((tid & 63) == 63) ws[tid >> 6] = x;
        __syncthreads();
        int add = carry;
        int w = tid >> 6;
        for (int j = 0; j < w; j++) add += ws[j];
        rowptr[i + tid] = add + x - v;      // exclusive
        __syncthreads();
        if (tid == 255) carry = add + x;
        __syncthreads();
    }
    if (tid == 0) rowptr[TNODE] = carry;
}
__global__ void csr_fill(const int* __restrict__ dst, const int* __restrict__ rowptr,
                         int* __restrict__ fillc, int* __restrict__ eidx)
{
    int e = blockIdx.x * 256 + threadIdx.x;
    int d = dst[e];
    int slot = rowptr[d] + atomicAdd(&fillc[d], 1);
    eidx[slot] = e;
}

// ------------- per-graph attention bias terms -------------
__global__ __launch_bounds__(256)
void term_kernel(const float* __restrict__ mn, const float* __restrict__ tgt_rel,
                 const float* __restrict__ Wa1, const float* __restrict__ Wd1,
                 const int* __restrict__ srcn, const int* __restrict__ tgtn,
                 float* __restrict__ term)
{
    __shared__ float Gs[HD];
    int b = blockIdx.x % Bg;
    int which = blockIdx.x / Bg;
    int c = threadIdx.x;
    float g;
    if (which == 0)
        g = mn[(size_t)srcn[b]*HD + c] + tgt_rel[b*HD + c] - mn[(size_t)tgtn[b]*HD + c];
    else
        g = tgt_rel[b*HD + c];
    Gs[c] = g;
    __syncthreads();
    const float* W = (which == 0) ? Wa1 : (Wd1 + (size_t)(which-1)*HD*512);
    float p = 0.f;
    for (int k = 0; k < HD; k += 4) {
        float4 w = ld4(W + (size_t)c*512 + 256 + k);
        p = fmaf(Gs[k], w.x, p); p = fmaf(Gs[k+1], w.y, p);
        p = fmaf(Gs[k+2], w.z, p); p = fmaf(Gs[k+3], w.w, p);
    }
    term[(size_t)which*Bg*HD + b*HD + c] = p;
}

__global__ void tgtrel_kernel(const float* __restrict__ rel_emb, const int* __restrict__ batch_rel,
                              float* __restrict__ tgt_rel)
{
    int b = blockIdx.x, c = threadIdx.x;
    tgt_rel[b*HD + c] = rel_emb[(size_t)batch_rel[b]*REMB + c];
}

__global__ void h0_kernel(const float* __restrict__ agg2, float* __restrict__ h0)
{
    int b = blockIdx.x, c = threadIdx.x;
    float m = -1e30f;
    for (int n = 0; n < Nn; n++)
        m = fmaxf(m, agg2[((size_t)b*Nn + n)*HD + c]);
    h0[b*HD + c] = m;
}

// ------------- convert w_hh to bf16: whbf[d][row][k] -------------
__global__ void whbf_kernel(const float* __restrict__ whf, const float* __restrict__ whb,
                            short* __restrict__ whbf)
{
    int idx = blockIdx.x * 256 + threadIdx.x;   // 2*768*256
    int d = idx / (768*256), rem = idx % (768*256);
    whbf[idx] = f2bf((d ? whb : whf)[rem]);
}

// ------------- GRU: 16 blocks x 512 thr; weight panel RESIDENT IN VGPRs -------------
// Each wave owns 6 n-tiles (192 VGPRs of bf16 weights, loaded once). Per step: MFMA
// (A = pre-split h from LDS, B = register weights), gates via LDS, epilogue. No weight
// re-reads -> removes the per-CU L2 ingestion wall.
__global__ __launch_bounds__(512, 2)
void gru_seq(const float* __restrict__ gi_f, const float* __restrict__ gi_b,
             const short* __restrict__ whbf,
             const float* __restrict__ bhf, const float* __restrict__ bhb,
             const float* __restrict__ h0,
             float* __restrict__ outf, float* __restrict__ outb)
{
    __shared__ float hsf[16][260];      // h state f32
    __shared__ short hsh[16][264];      // h bf16 hi
    __shared__ short hsl[16][264];      // h bf16 lo
    __shared__ float gates[768][17];    // [gate*256+h][seq]
    __shared__ float bsh[768];          // b_hh in LDS
    const int blk = blockIdx.x;         // dir*8 + grp
    const int d = blk >> 3, grp = blk & 7;
    const int tid = threadIdx.x;
    const int lane = tid & 63, wv = tid >> 6;   // 8 waves
    const int f16 = lane & 15;
    const int kb  = (lane >> 4) * 8;

    const short* wp0 = whbf + (size_t)d * 768 * 256;
    const float* gi  = d ? gi_b : gi_f;
    const float* bh  = d ? bhb : bhf;
    float* outp      = d ? outb : outf;

    for (int i = tid; i < 768; i += 512) bsh[i] = bh[i];

    // ---- weight panel -> registers: wave wv owns rows [(wv*6+j)*16, +16), j=0..5 ----
    bf8 wreg[6][8];
    #pragma unroll
    for (int j = 0; j < 6; j++) {
        int wr = (wv*6 + j) * 16 + f16;
        const short* wp = wp0 + (size_t)wr * 256 + kb;
        #pragma unroll
        for (int ks = 0; ks < 8; ks++)
            wreg[j][ks] = *(const bf8*)(wp + ks*32);
    }

    const int eseq = tid >> 5, ehb = tid & 31;      // epilogue: 8 h per thread
    {   // init h
        #pragma unroll
        for (int hh = 0; hh < 8; hh++) {
            int h = ehb + hh * 32;
            float v = h0[(size_t)(grp*16 + eseq) * HD + h];
            hsf[eseq][h] = v;
            short hi = f2bf(v);
            hsh[eseq][h] = hi;
            hsl[eseq][h] = f2bf(v - bf2f(hi));
        }
    }
    __syncthreads();

    for (int t = 0; t < Nn; t++) {
        int trow = d ? (Nn - 1 - t) : t;
        // --- gi prefetch (hides HBM latency under MFMA phase) ---
        float gr[8], gz[8], gn[8];
        {
            size_t girow = ((size_t)(grp*16 + eseq) * Nn + trow) * 768;
            #pragma unroll
            for (int hh = 0; hh < 8; hh++) {
                int h = ehb + hh * 32;
                gr[hh] = gi[girow + h];
                gz[hh] = gi[girow + 256 + h];
                gn[hh] = gi[girow + 512 + h];
            }
        }
        // --- MFMA: 6 tiles/wave, weights from registers ---
        #pragma unroll
        for (int j = 0; j < 6; j++) {
            f4 acc = {};
            #pragma unroll
            for (int ks = 0; ks < 8; ks++) {
                bf8 ahi = *(const bf8*)&hsh[f16][ks*32 + kb];
                bf8 alo = *(const bf8*)&hsl[f16][ks*32 + kb];
                acc = mfma_(ahi, wreg[j][ks], acc);
                acc = mfma_(alo, wreg[j][ks], acc);
            }
            #pragma unroll
            for (int reg = 0; reg < 4; reg++)
                gates[(wv*6 + j)*16 + f16][(lane >> 4)*4 + reg] = acc[reg];
        }
        __syncthreads();
        // --- epilogue: thread owns (eseq, ehb + hh*32) ---
        {
            size_t orow = ((size_t)(grp*16 + eseq) * Nn + trow) * HD;
            #pragma unroll
            for (int hh = 0; hh < 8; hh++) {
                int h = ehb + hh * 32;
                float R  = gates[h][eseq];
                float Z  = gates[256 + h][eseq];
                float NN = gates[512 + h][eseq];
                float hprev = hsf[eseq][h];
                float r = sigm_(gr[hh] + R + bsh[h]);
                float z = sigm_(gz[hh] + Z + bsh[256 + h]);
                float n = tanhf(gn[hh] + r * (NN + bsh[512 + h]));
                float nh = (1.f - z) * n + z * hprev;
                hsf[eseq][h] = nh;
                short hi = f2bf(nh);
                hsh[eseq][h] = hi;
                hsl[eseq][h] = f2bf(nh - bf2f(hi));
                outp[orow + h] = nh;
            }
        }
        __syncthreads();
    }
}

__global__ __launch_bounds__(256)
void final_kernel(const float* __restrict__ atom_h, const float* __restrict__ tgt_rel,
                  const int* __restrict__ srcn, const int* __restrict__ tgtn,
                  const float* __restrict__ Wl, const float* __restrict__ bl,
                  float* __restrict__ out)
{
    __shared__ float red[4];
    int b = blockIdx.x, c = threadIdx.x;
    float v = tanhf(atom_h[(size_t)srcn[b]*HD + c] + tgt_rel[b*HD + c]
                    - atom_h[(size_t)tgtn[b]*HD + c]);
    float p = v * Wl[c];
    #pragma unroll
    for (int off = 1; off < 64; off <<= 1) p += __shfl_xor(p, off);
    int wv = c >> 6;
    if ((c & 63) == 0) red[wv] = p;
    __syncthreads();
    if (c == 0) out[b] = red[0] + red[1] + red[2] + red[3] + bl[0];
}

extern "C" void kernel_launch(void* const* d_in, const int* in_sizes, int n_in,
                              void* d_out, int out_size, void* d_ws, size_t ws_size,
                              hipStream_t stream)
{
    const float* node_feat = (const float*)d_in[0];
    const float* rel_emb   = (const float*)d_in[1];
    const float* W_i_node  = (const float*)d_in[2];
    const float* W_i_edge  = (const float*)d_in[3];
    const float* Wa1       = (const float*)d_in[4];
    const float* Wa2       = (const float*)d_in[5];
    const float* W_h_atom  = (const float*)d_in[6];
    const float* W_h_bond  = (const float*)d_in[7];
    const float* Wd1       = (const float*)d_in[8];
    const float* Wd2       = (const float*)d_in[9];
    const float* W_comm    = (const float*)d_in[10];
    const float* gru_bias  = (const float*)d_in[11];
    const float* w_ih_f    = (const float*)d_in[12];
    const float* w_hh_f    = (const float*)d_in[13];
    const float* b_ih_f    = (const float*)d_in[14];
    const float* b_hh_f    = (const float*)d_in[15];
    const float* w_ih_b    = (const float*)d_in[16];
    const float* w_hh_b    = (const float*)d_in[17];
    const float* b_ih_b    = (const float*)d_in[18];
    const float* b_hh_b    = (const float*)d_in[19];
    const float* W_o       = (const float*)d_in[20];
    const float* b_o       = (const float*)d_in[21];
    const float* W_lin1    = (const float*)d_in[22];
    const float* b_lin1    = (const float*)d_in[23];
    const int* edge_src  = (const int*)d_in[24];
    const int* edge_dst  = (const int*)d_in[25];
    const int* edge_rel  = (const int*)d_in[26];
    const int* batch_rel = (const int*)d_in[27];
    const int* src_node  = (const int*)d_in[28];
    const int* tgt_node  = (const int*)d_in[29];
    float* out = (float*)d_out;

    float* ws = (float*)d_ws;
    size_t off = 0;
    auto alloc = [&](size_t n){ float* p = ws + off; off += n; return p; };
    float* tgt_rel    = alloc((size_t)Bg*HD);
    float* term       = alloc((size_t)3*Bg*HD);
    float* input_node = alloc((size_t)TNODE*HD);
    float* mn_a       = alloc((size_t)TNODE*HD);
    float* mn_b       = alloc((size_t)TNODE*HD);
    float* agg        = alloc((size_t)TNODE*HD);
    float* h0v        = alloc((size_t)Bg*HD);
    short* whbf       = (short*)alloc((size_t)2*768*256/2);
    float* sbuf       = alloc((size_t)TEDGE);
    int*   cnt        = (int*)alloc((size_t)TNODE);
    int*   fillc      = (int*)alloc((size_t)TNODE);
    int*   rowptr     = (int*)alloc((size_t)TNODE + 256);
    int*   eidx       = (int*)alloc((size_t)TEDGE);
    float* Sbuf       = alloc((size_t)TNODE*HD);
    float* Dbuf       = alloc((size_t)TNODE*HD);
    float* Rbuf       = alloc((size_t)256*HD);
    float* gi_f       = alloc((size_t)TNODE*768);
    float* gi_b       = alloc((size_t)TNODE*768);
    float* out_f      = alloc((size_t)TNODE*HD);
    float* out_b      = alloc((size_t)TNODE*HD);
    // aliases (lifetimes disjoint):
    float* agg2   = mn_a;        // after last attn/gather
    float* atom_h = input_node;  // after W_comm GEMM

    tgtrel_kernel<<<Bg, 256, 0, stream>>>(rel_emb, batch_rel, tgt_rel);
    whbf_kernel<<<1536, 256, 0, stream>>>(w_hh_f, w_hh_b, whbf);

    // ---- CSR build (dst-sorted incidence) ----
    zeroi_kernel<<<2*TNODE/256, 256, 0, stream>>>(cnt);     // zeros cnt AND fillc (adjacent)
    csr_count<<<TEDGE/256, 256, 0, stream>>>(edge_dst, cnt);
    csr_scan<<<1, 256, 0, stream>>>(cnt, rowptr);
    csr_fill<<<TEDGE/256, 256, 0, stream>>>(edge_dst, rowptr, fillc, eidx);

    // input_node = relu(node_feat @ W_i_node^T)
    mgemm<A_PLAIN, E_RELU><<<dim3(HD/128, TNODE/128), 256, 0, stream>>>(
        node_feat, nullptr, nullptr, W_i_node, nullptr, input_node,
        TNODE, HD, NEMB, NEMB, NEMB);

    // edge-feature factor tables: ie[e] = relu(S[src] + R[rel] + D[dst])
    mgemm<A_PLAIN, E_STORE><<<dim3(HD/128, TNODE/128), 256, 0, stream>>>(
        node_feat, nullptr, nullptr, W_i_edge + 0, nullptr, Sbuf,
        TNODE, HD, NEMB, NEMB, 512);
    mgemm<A_PLAIN, E_STORE><<<dim3(HD/128, TNODE/128), 256, 0, stream>>>(
        node_feat, nullptr, nullptr, W_i_edge + 384, nullptr, Dbuf,
        TNODE, HD, NEMB, NEMB, 512);
    mgemm<A_CLAMP, E_STORE><<<dim3(HD/128, 2), 256, 0, stream>>>(
        rel_emb, nullptr, nullptr, W_i_edge + 128, nullptr, Rbuf,
        200, HD, REMB, REMB, 512);

    term_kernel<<<3*Bg, 256, 0, stream>>>(input_node, tgt_rel, Wa1, Wd1,
                                          src_node, tgt_node, term);

    // ---- input attention scale + gather-aggregate ----
    mattn<0><<<TEDGE/64, 256, 0, stream>>>(Sbuf, Rbuf, Dbuf, Sbuf,
        edge_src, edge_rel, edge_dst, Wa1, Wa2, term, sbuf);
    agg_gather<0><<<TNODE/4, 256, 0, stream>>>(Sbuf, Rbuf, Dbuf, Sbuf,
        edge_src, edge_rel, rowptr, eidx, sbuf, agg);

    const float* mn_cur = input_node;
    float* bufs[2] = {mn_a, mn_b};
    for (int d = 0; d < 2; d++) {
        float* mn_next = bufs[d];
        float* tmp     = bufs[1-d];
        mgemm<A_ADD, E_RELU><<<dim3(2, TNODE/128), 256, 0, stream>>>(
            mn_cur, agg, nullptr, W_h_atom + (size_t)d*HD*HD, nullptr, mn_next,
            TNODE, HD, HD, HD, HD);
        mgemm<A_PLAIN, E_STORE><<<dim3(2, TNODE/128), 256, 0, stream>>>(
            mn_next, nullptr, nullptr, W_h_bond + (size_t)d*HD*HD, nullptr, tmp,
            TNODE, HD, HD, HD, HD);
        mattn<1><<<TEDGE/64, 256, 0, stream>>>(Sbuf, Rbuf, Dbuf, tmp,
            edge_src, edge_rel, edge_dst, Wd1 + (size_t)d*HD*512,
            Wd2 + (size_t)d*HD, term + (size_t)(1+d)*Bg*HD, sbuf);
        agg_gather<1><<<TNODE/4, 256, 0, stream>>>(Sbuf, Rbuf, Dbuf, tmp,
            edge_src, edge_rel, rowptr, eidx, sbuf, agg);
        mn_cur = mn_next;
    }

    // agg2 = concat([agg, mn, input_node]) @ W_comm^T   (agg2 aliases mn_a)
    mgemm<A_CAT3, E_STORE><<<dim3(2, TNODE/128), 256, 0, stream>>>(
        agg, (const float*)mn_cur, input_node, W_comm, nullptr, agg2,
        TNODE, HD, 3*HD, 0, 3*HD);

    h0_kernel<<<Bg, 256, 0, stream>>>(agg2, h0v);

    // gi = relu(agg2 + gru_bias) @ w_ih^T + b_ih   (both directions)
    mgemm<A_RELUB, E_BIAS><<<dim3(768/128, TNODE/128), 256, 0, stream>>>(
        agg2, gru_bias, nullptr, w_ih_f, b_ih_f, gi_f,
        TNODE, 768, HD, HD, HD);
    mgemm<A_RELUB, E_BIAS><<<dim3(768/128, TNODE/128), 256, 0, stream>>>(
        agg2, gru_bias, nullptr, w_ih_b, b_ih_b, gi_b,
        TNODE, 768, HD, HD, HD);

    gru_seq<<<16, 512, 0, stream>>>(gi_f, gi_b, whbf, b_hh_f, b_hh_b, h0v,
                                    out_f, out_b);

    // atom_h = relu(relu(concat(out_f,out_b)) @ W_o^T + b_o)
    mgemm<A_CAT2R, E_BIASRELU><<<dim3(2, TNODE/128), 256, 0, stream>>>(
        out_f, out_b, nullptr, W_o, b_o, atom_h,
        TNODE, HD, 2*HD, 0, 2*HD);

    final_kernel<<<Bg, 256, 0, stream>>>(atom_h, tgt_rel, src_node, tgt_node,
                                         W_lin1, b_lin1, out);
}